// Round 13
// baseline (544.456 us; speedup 1.0000x reference)
//
#include <hip/hip_runtime.h>
#include <math.h>

#define RR 3
#define NTOT 100000
#define NN0 80000
#define NN1 20000
#define NB 4096
#define NE1 300000
#define NE2 65536
#define FIN 128
#define HC1 256   // layer1: 2 heads x 128
#define HC2 128   // layer2: 1 head x 128

typedef __attribute__((ext_vector_type(8))) short bf16x8;
typedef __attribute__((ext_vector_type(4))) short s16x4;
typedef __attribute__((ext_vector_type(2))) short s16x2;
typedef __attribute__((ext_vector_type(4))) float f32x4;
typedef __attribute__((ext_vector_type(2))) float f32x2;

__device__ __forceinline__ float wave_red_sum(float v) {
    #pragma unroll
    for (int off = 32; off >= 1; off >>= 1) v += __shfl_xor(v, off, 64);
    return v;
}

__device__ __forceinline__ short f2bf(float x) {
    union { float f; unsigned u; } c; c.f = x;
    unsigned r = c.u + 0x7fffu + ((c.u >> 16) & 1u);
    return (short)(r >> 16);
}
__device__ __forceinline__ float bf2f(short s) {
    union { unsigned u; float f; } c; c.u = ((unsigned)(unsigned short)s) << 16;
    return c.f;
}

// fp8 e4m3 (OCP) HW converters
__device__ __forceinline__ float4 dec_fp8x4(unsigned w) {
    f32x2 lo = __builtin_amdgcn_cvt_pk_f32_fp8((int)w, false);
    f32x2 hi = __builtin_amdgcn_cvt_pk_f32_fp8((int)w, true);
    float4 r = { lo[0], lo[1], hi[0], hi[1] };
    return r;
}
__device__ __forceinline__ float2 dec_fp8x2(unsigned w) {
    f32x2 lo = __builtin_amdgcn_cvt_pk_f32_fp8((int)w, false);
    float2 r = { lo[0], lo[1] };
    return r;
}
__device__ __forceinline__ unsigned enc_fp8x4(float a, float b, float c, float d) {
    int w = __builtin_amdgcn_cvt_pk_fp8_f32(a, b, 0, false);
    w = __builtin_amdgcn_cvt_pk_fp8_f32(c, d, w, true);
    return (unsigned)w;
}

__device__ __forceinline__ float4 ld4(const float* p) { return *(const float4*)p; }
__device__ __forceinline__ float4 ld4(const short* p) {
    s16x4 v = *(const s16x4*)p;
    float4 r = { bf2f(v[0]), bf2f(v[1]), bf2f(v[2]), bf2f(v[3]) };
    return r;
}
__device__ __forceinline__ float2 ld2(const float* p) { return *(const float2*)p; }
__device__ __forceinline__ float2 ld2(const short* p) {
    s16x2 v = *(const s16x2*)p;
    float2 r = { bf2f(v[0]), bf2f(v[1]) };
    return r;
}

// ---------- convert features f32 -> bf16 ----------
__global__ void __launch_bounds__(256)
fcvt_k(const float* __restrict__ f, short* __restrict__ o, int n4) {
    int i = blockIdx.x * 256 + threadIdx.x;
    if (i < n4) {
        float4 v = *(const float4*)(f + (size_t)i * 4);
        s16x4 s = { f2bf(v.x), f2bf(v.y), f2bf(v.z), f2bf(v.w) };
        *(s16x4*)(o + (size_t)i * 4) = s;
    }
}

// ---------- pack 4 weight mats per replica into MFMA B-fragment order ----------
template<int K, int N>
__global__ void __launch_bounds__(256)
wpack_k(const float* __restrict__ W0, const float* __restrict__ W1,
        const float* __restrict__ W2, const float* __restrict__ W3,
        short* __restrict__ P) {
    constexpr int KS = K / 32;
    const int m = blockIdx.y, r = blockIdx.z;
    const float* W = (m == 0 ? W0 : m == 1 ? W1 : m == 2 ? W2 : W3) + (size_t)r * K * N;
    short* o = P + ((size_t)(r * 4 + m)) * K * N;
    for (int i = blockIdx.x * 256 + threadIdx.x; i < K * N; i += gridDim.x * 256) {
        int j = i & 7, lane = (i >> 3) & 63, f = i >> 9;
        int ks = f % KS, nt = f / KS;
        int k = ks * 32 + (lane >> 4) * 8 + j;
        int n = nt * 16 + (lane & 15);
        o[i] = f2bf(W[(size_t)k * N + n]);
    }
}

// ---------- MFMA GEMM, low-pressure tiling ----------
// OT: float=f32, short=bf16, unsigned char=fp8(e4m3)
template<int K, int N, typename OT0, typename OT1>
__global__ void __launch_bounds__(256)
gemm2l(const short* __restrict__ xbf, int ldx, const int* __restrict__ gidx,
       const short* __restrict__ P0, const float* __restrict__ b0, OT0* __restrict__ out0,
       const short* __restrict__ P1, const float* __restrict__ b1, OT1* __restrict__ out1)
{
    constexpr int NT = N / 16;
    constexpr int NW = NT / 4;
    constexpr int KS = K / 32;
    constexpr int MT = 2;
    const int lane = threadIdx.x & 63;
    const int wid  = threadIdx.x >> 6;
    const int rowbase = blockIdx.x * (MT * 16);

    const short* ap[MT];
    #pragma unroll
    for (int mt = 0; mt < MT; ++mt) {
        int arow = rowbase + mt * 16 + (lane & 15);
        int srow = gidx ? gidx[arow] : arow;
        ap[mt] = xbf + (size_t)srow * ldx + ((lane >> 4) * 8);
    }
    const int fb = lane * 8;

    f32x4 acc[MT][NW][2];
    #pragma unroll
    for (int mt = 0; mt < MT; ++mt)
        #pragma unroll
        for (int j = 0; j < NW; ++j) { acc[mt][j][0] = (f32x4)(0.0f); acc[mt][j][1] = (f32x4)(0.0f); }

    for (int ks = 0; ks < KS; ++ks) {
        bf16x8 a[MT];
        #pragma unroll
        for (int mt = 0; mt < MT; ++mt) a[mt] = *(const bf16x8*)(ap[mt] + ks * 32);
        #pragma unroll
        for (int j = 0; j < NW; ++j) {
            const int nt = wid * NW + j;
            const int off = ((nt * KS + ks) << 9) + fb;
            bf16x8 bv0 = *(const bf16x8*)(P0 + off);
            bf16x8 bv1 = *(const bf16x8*)(P1 + off);
            #pragma unroll
            for (int mt = 0; mt < MT; ++mt) {
                acc[mt][j][0] = __builtin_amdgcn_mfma_f32_16x16x32_bf16(a[mt], bv0, acc[mt][j][0], 0, 0, 0);
                acc[mt][j][1] = __builtin_amdgcn_mfma_f32_16x16x32_bf16(a[mt], bv1, acc[mt][j][1], 0, 0, 0);
            }
        }
    }

    __shared__ float ls[MT * 16][N + 4];
    constexpr int CPT = (MT * 16) * N / 8 / 256;
    const int tid = threadIdx.x;

    #pragma unroll
    for (int mat = 0; mat < 2; ++mat) {
        if (mat) __syncthreads();
        const float* bias = mat ? b1 : b0;
        #pragma unroll
        for (int j = 0; j < NW; ++j) {
            const int nt = wid * NW + j;
            const float bb = bias[nt * 16 + (lane & 15)];
            #pragma unroll
            for (int mt = 0; mt < MT; ++mt)
                #pragma unroll
                for (int rg = 0; rg < 4; ++rg)
                    ls[mt * 16 + (lane >> 4) * 4 + rg][nt * 16 + (lane & 15)] =
                        acc[mt][j][mat][rg] + bb;
        }
        __syncthreads();
        #pragma unroll
        for (int c2 = 0; c2 < CPT; ++c2) {
            const int chunk = c2 * 256 + tid;
            const int row = chunk / (N / 8);
            const int colb = (chunk % (N / 8)) * 8;
            float v[8];
            #pragma unroll
            for (int i = 0; i < 8; ++i) v[i] = ls[row][colb + i];
            const size_t gbase = (size_t)(rowbase + row) * N + colb;
            if (mat == 0) {
                if constexpr (sizeof(OT0) == 1) {
                    uint2 u = { enc_fp8x4(v[0],v[1],v[2],v[3]), enc_fp8x4(v[4],v[5],v[6],v[7]) };
                    *(uint2*)((unsigned char*)out0 + gbase) = u;
                } else if constexpr (sizeof(OT0) == 2) {
                    bf16x8 s;
                    #pragma unroll
                    for (int i = 0; i < 8; ++i) s[i] = f2bf(v[i]);
                    *(bf16x8*)(out0 + gbase) = s;
                } else {
                    float4 lo = { v[0], v[1], v[2], v[3] }, hi = { v[4], v[5], v[6], v[7] };
                    *(float4*)(out0 + gbase) = lo;
                    *(float4*)(out0 + gbase + 4) = hi;
                }
            } else {
                if constexpr (sizeof(OT1) == 1) {
                    uint2 u = { enc_fp8x4(v[0],v[1],v[2],v[3]), enc_fp8x4(v[4],v[5],v[6],v[7]) };
                    *(uint2*)((unsigned char*)out1 + gbase) = u;
                } else if constexpr (sizeof(OT1) == 2) {
                    bf16x8 s;
                    #pragma unroll
                    for (int i = 0; i < 8; ++i) s[i] = f2bf(v[i]);
                    *(bf16x8*)(out1 + gbase) = s;
                } else {
                    float4 lo = { v[0], v[1], v[2], v[3] }, hi = { v[4], v[5], v[6], v[7] };
                    *(float4*)(out1 + gbase) = lo;
                    *(float4*)(out1 + gbase + 4) = hi;
                }
            }
        }
    }
}

// ================= two-level CSR build =================
// a1/b/a2: bucket edges by KEY into windows (LDS atomics, windowed writes).
// Variants: *_a1/a2 read (src,dst) edge-list keyed on dst>>9;
//           seg_a1/a2 read edge-list keyed on src>>SSH (locality pre-sort);
//           *_a1p/a2p read packed u64 stream keyed on dst>>9.

template<int TS>
__global__ void __launch_bounds__(256)
csr_a1(const int* __restrict__ ei, int E, int R, int T, int* __restrict__ cnt_tr) {
    const int r = blockIdx.y, tile = blockIdx.x;
    const int* dst = ei + (size_t)r * 2 * E + E;
    __shared__ int h[64];
    for (int i = threadIdx.x; i < R; i += 256) h[i] = 0;
    __syncthreads();
    const int e0 = tile * TS, e1 = min(e0 + TS, E);
    for (int e = e0 + threadIdx.x; e < e1; e += 256) atomicAdd(&h[dst[e] >> 9], 1);
    __syncthreads();
    for (int i = threadIdx.x; i < R; i += 256)
        cnt_tr[((size_t)r * R + i) * T + tile] = h[i];
}
template<int TS, int SSH>
__global__ void __launch_bounds__(256)
seg_a1(const int* __restrict__ ei, int E, int R, int T, int* __restrict__ cnt_tr) {
    const int r = blockIdx.y, tile = blockIdx.x;
    const int* src = ei + (size_t)r * 2 * E;
    __shared__ int h[64];
    for (int i = threadIdx.x; i < R; i += 256) h[i] = 0;
    __syncthreads();
    const int e0 = tile * TS, e1 = min(e0 + TS, E);
    for (int e = e0 + threadIdx.x; e < e1; e += 256) atomicAdd(&h[src[e] >> SSH], 1);
    __syncthreads();
    for (int i = threadIdx.x; i < R; i += 256)
        cnt_tr[((size_t)r * R + i) * T + tile] = h[i];
}
template<int TS>
__global__ void __launch_bounds__(256)
csr_a1p(const unsigned long long* __restrict__ scr_s, int E, int R, int T, int* __restrict__ cnt_tr) {
    const int r = blockIdx.y, tile = blockIdx.x;
    const unsigned long long* sc = scr_s + (size_t)r * E;
    __shared__ int h[64];
    for (int i = threadIdx.x; i < R; i += 256) h[i] = 0;
    __syncthreads();
    const int e0 = tile * TS, e1 = min(e0 + TS, E);
    for (int e = e0 + threadIdx.x; e < e1; e += 256) atomicAdd(&h[(int)(sc[e] >> 32) >> 9], 1);
    __syncthreads();
    for (int i = threadIdx.x; i < R; i += 256)
        cnt_tr[((size_t)r * R + i) * T + tile] = h[i];
}
__global__ void __launch_bounds__(64)
csr_b(const int* __restrict__ cnt_tr, int R, int T, int E, int nbins,
      int* __restrict__ base_tr, int* __restrict__ rbase, int* __restrict__ offsg) {
    const int r = blockIdx.x;
    __shared__ int tot[64];
    const int t = threadIdx.x;
    if (t < R) {
        const int* c = cnt_tr + ((size_t)r * R + t) * T;
        int s = 0;
        for (int i = 0; i < T; ++i) s += c[i];
        tot[t] = s;
    }
    __syncthreads();
    if (t == 0) { int run = 0; for (int i = 0; i < R; ++i) { int c = tot[i]; tot[i] = run; run += c; } }
    __syncthreads();
    if (t < R) {
        const int* c = cnt_tr + ((size_t)r * R + t) * T;
        int* b = base_tr + ((size_t)r * R + t) * T;
        int run = tot[t];
        for (int i = 0; i < T; ++i) { b[i] = run; run += c[i]; }
        rbase[(size_t)r * (R + 1) + t] = tot[t];
    }
    if (t == 0) {
        rbase[(size_t)r * (R + 1) + R] = E;
        offsg[(size_t)r * (nbins + 1) + nbins] = E;
    }
}
template<int TS, int SSH>
__global__ void __launch_bounds__(256)
seg_a2(const int* __restrict__ ei, int E, int R, int T,
       const int* __restrict__ base_tr, unsigned long long* __restrict__ scr_s) {
    const int r = blockIdx.y, tile = blockIdx.x;
    const int* src = ei + (size_t)r * 2 * E;
    const int* dst = src + E;
    __shared__ int cur[64];
    for (int i = threadIdx.x; i < R; i += 256)
        cur[i] = base_tr[((size_t)r * R + i) * T + tile];
    __syncthreads();
    unsigned long long* sc = scr_s + (size_t)r * E;
    const int e0 = tile * TS, e1 = min(e0 + TS, E);
    for (int e = e0 + threadIdx.x; e < e1; e += 256) {
        int s = src[e];
        int pos = atomicAdd(&cur[s >> SSH], 1);
        sc[pos] = ((unsigned long long)(unsigned)dst[e] << 32) | (unsigned)s;
    }
}
template<int TS>
__global__ void __launch_bounds__(256)
csr_a2p(const unsigned long long* __restrict__ scr_s, int E, int R, int T,
        const int* __restrict__ base_tr, unsigned long long* __restrict__ scratch) {
    const int r = blockIdx.y, tile = blockIdx.x;
    const unsigned long long* in = scr_s + (size_t)r * E;
    __shared__ int cur[64];
    for (int i = threadIdx.x; i < R; i += 256)
        cur[i] = base_tr[((size_t)r * R + i) * T + tile];
    __syncthreads();
    unsigned long long* sc = scratch + (size_t)r * E;
    const int e0 = tile * TS, e1 = min(e0 + TS, E);
    for (int e = e0 + threadIdx.x; e < e1; e += 256) {
        unsigned long long v = in[e];
        int pos = atomicAdd(&cur[(int)(v >> 32) >> 9], 1);
        sc[pos] = v;
    }
}
template<int TS>
__global__ void __launch_bounds__(256)
csr_a2(const int* __restrict__ ei, int E, int R, int T,
       const int* __restrict__ base_tr, unsigned long long* __restrict__ scratch) {
    const int r = blockIdx.y, tile = blockIdx.x;
    const int* src = ei + (size_t)r * 2 * E;
    const int* dst = src + E;
    __shared__ int cur[64];
    for (int i = threadIdx.x; i < R; i += 256)
        cur[i] = base_tr[((size_t)r * R + i) * T + tile];
    __syncthreads();
    unsigned long long* sc = scratch + (size_t)r * E;
    const int e0 = tile * TS, e1 = min(e0 + TS, E);
    for (int e = e0 + threadIdx.x; e < e1; e += 256) {
        int d = dst[e];
        int pos = atomicAdd(&cur[d >> 9], 1);
        sc[pos] = ((unsigned long long)(unsigned)d << 32) | (unsigned)src[e];
    }
}
__global__ void __launch_bounds__(256)
csr_c(const unsigned long long* __restrict__ scratch, const int* __restrict__ rbase,
      int E, int R, int nbins, int* __restrict__ offsg, int* __restrict__ slistg) {
    const int r = blockIdx.y, range = blockIdx.x;
    const unsigned long long* sc = scratch + (size_t)r * E;
    const int* rb = rbase + (size_t)r * (R + 1);
    int* offs = offsg + (size_t)r * (nbins + 1);
    int* slist = slistg + (size_t)r * E;
    const int s0 = rb[range], s1 = rb[range + 1];
    const int lo = range << 9;
    const int nb = min(512, nbins - lo);
    __shared__ int h0[512];
    __shared__ int cur[512];
    __shared__ int ps[256];
    const int tid = threadIdx.x;
    h0[2*tid] = 0; h0[2*tid+1] = 0;
    __syncthreads();
    for (int i = s0 + tid; i < s1; i += 256)
        atomicAdd(&h0[(int)(sc[i] >> 32) - lo], 1);
    __syncthreads();
    const int a_ = h0[2*tid], b_ = h0[2*tid+1];
    ps[tid] = a_ + b_;
    __syncthreads();
    for (int off = 1; off < 256; off <<= 1) {
        int v = (tid >= off) ? ps[tid - off] : 0;
        __syncthreads();
        ps[tid] += v;
        __syncthreads();
    }
    const int base = (tid ? ps[tid - 1] : 0) + s0;
    const int o0 = base, o1 = base + a_;
    if (2*tid     < nb) offs[lo + 2*tid]     = o0;
    if (2*tid + 1 < nb) offs[lo + 2*tid + 1] = o1;
    cur[2*tid] = o0; cur[2*tid+1] = o1;
    __syncthreads();
    for (int i = s0 + tid; i < s1; i += 256) {
        unsigned long long v = sc[i];
        int d = (int)(v >> 32) - lo;
        int pos = atomicAdd(&cur[d], 1);
        slist[pos] = (int)(v & 0xffffffffu);
    }
}

// ---------- fused layer-1 attention, edge-PAIR pipelined; K fp8, V bf16 ----------
__global__ void __launch_bounds__(64)
attn1_k(const int* __restrict__ offs, const int* __restrict__ slist,
        const short* __restrict__ qb, const unsigned char* __restrict__ kb,
        const short* __restrict__ vb,
        const short* __restrict__ xr, const float* __restrict__ wb,
        const float* __restrict__ g, const float* __restrict__ bbn,
        const float* __restrict__ mean, const float* __restrict__ var,
        short* __restrict__ hb)
{
    const int n = blockIdx.x;
    const int lane = threadIdx.x;
    const int c0 = lane * 4;
    const int lo = offs[n], hi = offs[n+1];
    const float4 q = ld4(qb + (size_t)n * HC1 + c0);
    const float scale = 0.088388347648318447f;   // 1/sqrt(128)

    float m = -INFINITY, s = 0.f;
    float a0 = 0.f, a1 = 0.f, a2 = 0.f, a3 = 0.f;
    unsigned kw0 = 0, kw1 = 0;
    float4 v0 = {0,0,0,0}, v1 = {0,0,0,0};
    if (lo < hi) {
        int sr = slist[lo];
        kw0 = *(const unsigned*)(kb + (size_t)sr * HC1 + c0);
        v0 = ld4(vb + (size_t)sr * HC1 + c0);
    }
    if (lo + 1 < hi) {
        int sr = slist[lo + 1];
        kw1 = *(const unsigned*)(kb + (size_t)sr * HC1 + c0);
        v1 = ld4(vb + (size_t)sr * HC1 + c0);
    }
    for (int i = lo; i < hi; i += 2) {
        unsigned kwn0 = 0, kwn1 = 0;
        float4 vn0 = {0,0,0,0}, vn1 = {0,0,0,0};
        if (i + 2 < hi) {
            int sr = slist[i + 2];
            kwn0 = *(const unsigned*)(kb + (size_t)sr * HC1 + c0);
            vn0 = ld4(vb + (size_t)sr * HC1 + c0);
        }
        if (i + 3 < hi) {
            int sr = slist[i + 3];
            kwn1 = *(const unsigned*)(kb + (size_t)sr * HC1 + c0);
            vn1 = ld4(vb + (size_t)sr * HC1 + c0);
        }
        const float4 k0 = dec_fp8x4(kw0);
        const float4 k1 = dec_fp8x4(kw1);
        float p0 = q.x*k0.x + q.y*k0.y + q.z*k0.z + q.w*k0.w;
        float p1 = q.x*k1.x + q.y*k1.y + q.z*k1.z + q.w*k1.w;
        #pragma unroll
        for (int off = 16; off >= 1; off >>= 1) {
            p0 += __shfl_xor(p0, off, 64);
            p1 += __shfl_xor(p1, off, 64);
        }
        const float alpha0 = p0 * scale;
        const float alpha1 = (i + 1 < hi) ? p1 * scale : -INFINITY;
        float mn = fmaxf(m, alpha0);
        float rs = __expf(m - mn);
        float pp = __expf(alpha0 - mn);
        s  = s*rs + pp;
        a0 = a0*rs + pp*v0.x; a1 = a1*rs + pp*v0.y;
        a2 = a2*rs + pp*v0.z; a3 = a3*rs + pp*v0.w;
        m = mn;
        mn = fmaxf(m, alpha1);
        rs = __expf(m - mn);
        pp = __expf(alpha1 - mn);
        s  = s*rs + pp;
        a0 = a0*rs + pp*v1.x; a1 = a1*rs + pp*v1.y;
        a2 = a2*rs + pp*v1.z; a3 = a3*rs + pp*v1.w;
        m = mn;
        kw0 = kwn0; v0 = vn0; kw1 = kwn1; v1 = vn1;
    }
    const float inv = (s > 0.f) ? 1.f/s : 0.f;
    const float att[4] = { a0*inv, a1*inv, a2*inv, a3*inv };

    const float4 x4 = ld4(xr + (size_t)n * HC1 + c0);
    const float xx[4] = { x4.x, x4.y, x4.z, x4.w };
    float d = 0.f;
    #pragma unroll
    for (int j = 0; j < 4; ++j) {
        int c = c0 + j;
        d += att[j]*wb[c] + xx[j]*wb[HC1 + c] + (att[j]-xx[j])*wb[2*HC1 + c];
    }
    d = wave_red_sum(d);
    const float beta = 1.f / (1.f + __expf(-d));
    s16x4 hv4;
    #pragma unroll
    for (int j = 0; j < 4; ++j) {
        int c = c0 + j;
        float hv = beta*xx[j] + (1.f-beta)*att[j];
        hv = (hv - mean[c]) * rsqrtf(var[c] + 1e-5f) * g[c] + bbn[c];
        hv = hv > 0.f ? hv : expm1f(hv);
        hv4[j] = f2bf(hv);
    }
    *(s16x4*)(hb + (size_t)n * HC1 + c0) = hv4;
}

// ---------- fused layer-2 attention, edge-PAIR pipelined; K fp8, V bf16 ----------
__global__ void __launch_bounds__(64)
attn2_k(const int* __restrict__ offs, const int* __restrict__ slist,
        const short* __restrict__ qb, const unsigned char* __restrict__ kb,
        const short* __restrict__ vb,
        const short* __restrict__ xr, const float* __restrict__ wb,
        float* __restrict__ outp, int colofs)
{
    const int n = blockIdx.x;
    const int lane = threadIdx.x;
    const int c0 = lane * 2;
    const int lo = offs[n], hi = offs[n+1];
    const float2 q = ld2(qb + (size_t)n * HC2 + c0);
    const float scale = 0.088388347648318447f;   // 1/sqrt(128)

    float m = -INFINITY, s = 0.f;
    float a0 = 0.f, a1 = 0.f;
    unsigned kw0 = 0, kw1 = 0;
    float2 v0 = {0,0}, v1 = {0,0};
    if (lo < hi) {
        int sr = slist[lo];
        kw0 = *(const unsigned short*)(kb + (size_t)sr * HC2 + c0);
        v0 = ld2(vb + (size_t)sr * HC2 + c0);
    }
    if (lo + 1 < hi) {
        int sr = slist[lo + 1];
        kw1 = *(const unsigned short*)(kb + (size_t)sr * HC2 + c0);
        v1 = ld2(vb + (size_t)sr * HC2 + c0);
    }
    for (int i = lo; i < hi; i += 2) {
        unsigned kwn0 = 0, kwn1 = 0;
        float2 vn0 = {0,0}, vn1 = {0,0};
        if (i + 2 < hi) {
            int sr = slist[i + 2];
            kwn0 = *(const unsigned short*)(kb + (size_t)sr * HC2 + c0);
            vn0 = ld2(vb + (size_t)sr * HC2 + c0);
        }
        if (i + 3 < hi) {
            int sr = slist[i + 3];
            kwn1 = *(const unsigned short*)(kb + (size_t)sr * HC2 + c0);
            vn1 = ld2(vb + (size_t)sr * HC2 + c0);
        }
        const float2 k0 = dec_fp8x2(kw0);
        const float2 k1 = dec_fp8x2(kw1);
        float p0 = q.x*k0.x + q.y*k0.y;
        float p1 = q.x*k1.x + q.y*k1.y;
        #pragma unroll
        for (int off = 32; off >= 1; off >>= 1) {
            p0 += __shfl_xor(p0, off, 64);
            p1 += __shfl_xor(p1, off, 64);
        }
        const float alpha0 = p0 * scale;
        const float alpha1 = (i + 1 < hi) ? p1 * scale : -INFINITY;
        float mn = fmaxf(m, alpha0);
        float rs = __expf(m - mn);
        float pp = __expf(alpha0 - mn);
        s  = s*rs + pp;
        a0 = a0*rs + pp*v0.x; a1 = a1*rs + pp*v0.y;
        m = mn;
        mn = fmaxf(m, alpha1);
        rs = __expf(m - mn);
        pp = __expf(alpha1 - mn);
        s  = s*rs + pp;
        a0 = a0*rs + pp*v1.x; a1 = a1*rs + pp*v1.y;
        m = mn;
        kw0 = kwn0; v0 = vn0; kw1 = kwn1; v1 = vn1;
    }
    const float inv = (s > 0.f) ? 1.f/s : 0.f;
    const float att0 = a0*inv, att1 = a1*inv;

    const float2 x2 = ld2(xr + (size_t)n * HC2 + c0);
    float d = att0*wb[c0] + att1*wb[c0+1]
            + x2.x*wb[HC2+c0] + x2.y*wb[HC2+c0+1]
            + (att0-x2.x)*wb[2*HC2+c0] + (att1-x2.y)*wb[2*HC2+c0+1];
    d = wave_red_sum(d);
    const float beta = 1.f/(1.f+__expf(-d));
    outp[(size_t)n*(RR*HC2) + colofs + c0]     = beta*x2.x + (1.f-beta)*att0;
    outp[(size_t)n*(RR*HC2) + colofs + c0 + 1] = beta*x2.y + (1.f-beta)*att1;
}

extern "C" void kernel_launch(void* const* d_in, const int* in_sizes, int n_in,
                              void* d_out, int out_size, void* d_ws, size_t ws_size,
                              hipStream_t stream)
{
    const float* features = (const float*)d_in[0];
    const int*   n_ids    = (const int*)d_in[1];
    const int*   ei1      = (const int*)d_in[2];
    const int*   ei2      = (const int*)d_in[3];
    const float* wq1 = (const float*)d_in[4];  const float* bq1 = (const float*)d_in[5];
    const float* wk1 = (const float*)d_in[6];  const float* bk1 = (const float*)d_in[7];
    const float* wv1 = (const float*)d_in[8];  const float* bv1 = (const float*)d_in[9];
    const float* ws1 = (const float*)d_in[10]; const float* bs1 = (const float*)d_in[11];
    const float* wbeta1 = (const float*)d_in[12];
    const float* bn_g = (const float*)d_in[13]; const float* bn_b = (const float*)d_in[14];
    const float* bn_m = (const float*)d_in[15]; const float* bn_v = (const float*)d_in[16];
    const float* wq2 = (const float*)d_in[17]; const float* bq2 = (const float*)d_in[18];
    const float* wk2 = (const float*)d_in[19]; const float* bk2 = (const float*)d_in[20];
    const float* wv2 = (const float*)d_in[21]; const float* bv2 = (const float*)d_in[22];
    const float* ws2 = (const float*)d_in[23]; const float* bs2 = (const float*)d_in[24];
    const float* wbeta2 = (const float*)d_in[25];
    float* outp = (float*)d_out;

    // CSR build geometry
    constexpr int TS = 8192;
    constexpr int T1 = (NE1 + TS - 1) / TS;   // 37
    constexpr int T2 = (NE2 + TS - 1) / TS;   // 8
    constexpr int R1 = (NN1 + 511) >> 9;      // 40
    constexpr int R2 = (NB  + 511) >> 9;      // 8
    constexpr int SSH = 11;                   // src segment = 2048 rows (~1.6MB k+v)
    constexpr int RS1 = (NN0 + (1 << SSH) - 1) >> SSH;  // 40 src segments

    char* p = (char*)d_ws;
    auto alloc = [&](size_t bytes) { char* q = p; p += (bytes + 255) & ~(size_t)255; return q; };
    unsigned char* k1b = (unsigned char*)alloc((size_t)NN0*HC1);     // 20.5 MB fp8
    short* v1b  = (short*)alloc(sizeof(short)*(size_t)NN0*HC1);      // 41 MB bf16
    short* q1b  = (short*)alloc(sizeof(short)*(size_t)NN1*HC1);
    short* xr1  = (short*)alloc(sizeof(short)*(size_t)NN1*HC1);
    short* hbf  = (short*)alloc(sizeof(short)*(size_t)NN1*HC1);
    short* xbf  = (short*)alloc(sizeof(short)*(size_t)NTOT*FIN);
    short* wt1  = (short*)alloc(sizeof(short)*(size_t)RR*4*FIN*HC1);
    short* wt2  = (short*)alloc(sizeof(short)*(size_t)RR*4*HC1*HC2);
    unsigned char* k2b = (unsigned char*)alloc((size_t)NN1*HC2);
    short* v2b  = (short*)alloc(sizeof(short)*(size_t)NN1*HC2);
    short* q2b  = (short*)alloc(sizeof(short)*(size_t)NB*HC2);
    short* xr2  = (short*)alloc(sizeof(short)*(size_t)NB*HC2);
    // CSR state (all replicas)
    int* offs1  = (int*)alloc(sizeof(int)*(size_t)RR*(NN1+1));
    int* slist1 = (int*)alloc(sizeof(int)*(size_t)RR*NE1);
    int* offs2  = (int*)alloc(sizeof(int)*(size_t)RR*(NB+1));
    int* slist2 = (int*)alloc(sizeof(int)*(size_t)RR*NE2);
    unsigned long long* scr1  = (unsigned long long*)alloc(sizeof(unsigned long long)*(size_t)RR*NE1);
    unsigned long long* scrs1 = (unsigned long long*)alloc(sizeof(unsigned long long)*(size_t)RR*NE1);
    unsigned long long* scr2  = (unsigned long long*)alloc(sizeof(unsigned long long)*(size_t)RR*NE2);
    int* cnt_tr1  = (int*)alloc(sizeof(int)*(size_t)RR*R1*T1);
    int* base_tr1 = (int*)alloc(sizeof(int)*(size_t)RR*R1*T1);
    int* rbase1   = (int*)alloc(sizeof(int)*(size_t)RR*(R1+1));
    int* cnt_tr2  = (int*)alloc(sizeof(int)*(size_t)RR*R2*T2);
    int* base_tr2 = (int*)alloc(sizeof(int)*(size_t)RR*R2*T2);
    int* rbase2   = (int*)alloc(sizeof(int)*(size_t)RR*(R2+1));
    int* cnt_sr1  = (int*)alloc(sizeof(int)*(size_t)RR*RS1*T1);
    int* base_sr1 = (int*)alloc(sizeof(int)*(size_t)RR*RS1*T1);
    int* rbase_s1 = (int*)alloc(sizeof(int)*(size_t)RR*(RS1+1));
    int* dummy1   = (int*)alloc(sizeof(int)*(size_t)RR*(RS1+1));
    (void)ws_size; (void)in_sizes; (void)n_in; (void)out_size;

    // ---- prologue: conversions + weight packing ----
    fcvt_k<<<(NTOT*FIN/4 + 255)/256, 256, 0, stream>>>(features, xbf, NTOT*FIN/4);
    {
        dim3 g1(128, 4, RR);
        wpack_k<FIN, HC1><<<g1, 256, 0, stream>>>(wq1, wk1, wv1, ws1, wt1);
        dim3 g2(128, 4, RR);
        wpack_k<HC1, HC2><<<g2, 256, 0, stream>>>(wq2, wk2, wv2, ws2, wt2);
    }

    // ---- CSR builds ----
    {
        dim3 ga1(T1, RR), ga2(T2, RR);
        // layer 1: pre-bucket edges by src segment (locality), then dst-CSR
        seg_a1<TS, SSH><<<ga1, 256, 0, stream>>>(ei1, NE1, RS1, T1, cnt_sr1);
        csr_b<<<RR, 64, 0, stream>>>(cnt_sr1, RS1, T1, NE1, RS1, base_sr1, rbase_s1, dummy1);
        seg_a2<TS, SSH><<<ga1, 256, 0, stream>>>(ei1, NE1, RS1, T1, base_sr1, scrs1);
        csr_a1p<TS><<<ga1, 256, 0, stream>>>(scrs1, NE1, R1, T1, cnt_tr1);
        csr_b<<<RR, 64, 0, stream>>>(cnt_tr1, R1, T1, NE1, NN1, base_tr1, rbase1, offs1);
        csr_a2p<TS><<<ga1, 256, 0, stream>>>(scrs1, NE1, R1, T1, base_tr1, scr1);
        // layer 2: kv2 is L2-resident (10MB) -> no locality pre-sort needed
        csr_a1<TS><<<ga2, 256, 0, stream>>>(ei2, NE2, R2, T2, cnt_tr2);
        csr_b<<<RR, 64, 0, stream>>>(cnt_tr2, R2, T2, NE2, NB,  base_tr2, rbase2, offs2);
        csr_a2<TS><<<ga2, 256, 0, stream>>>(ei2, NE2, R2, T2, base_tr2, scr2);
        dim3 gc1(R1, RR), gc2(R2, RR);
        csr_c<<<gc1, 256, 0, stream>>>(scr1, rbase1, NE1, R1, NN1, offs1, slist1);
        csr_c<<<gc2, 256, 0, stream>>>(scr2, rbase2, NE2, R2, NB,  offs2, slist2);
    }

    const size_t WSZ = (size_t)FIN*HC1;

    for (int r = 0; r < RR; ++r) {
        const int* nid  = n_ids + (size_t)r*NN0;
        const short* ptq1 = wt1 + ((size_t)r*4 + 0)*WSZ;
        const short* ptk1 = wt1 + ((size_t)r*4 + 1)*WSZ;
        const short* ptv1 = wt1 + ((size_t)r*4 + 2)*WSZ;
        const short* pts1 = wt1 + ((size_t)r*4 + 3)*WSZ;
        const short* ptq2 = wt2 + ((size_t)r*4 + 0)*WSZ;
        const short* ptk2 = wt2 + ((size_t)r*4 + 1)*WSZ;
        const short* ptv2 = wt2 + ((size_t)r*4 + 2)*WSZ;
        const short* pts2 = wt2 + ((size_t)r*4 + 3)*WSZ;

        // ---- layer 1 projections (MFMA, fused gather; K fp8, V bf16) ----
        gemm2l<FIN, HC1, unsigned char, short><<<NN0/32, 256, 0, stream>>>(
            xbf, FIN, nid, ptk1, bk1 + r*HC1, k1b, ptv1, bv1 + r*HC1, v1b);
        gemm2l<FIN, HC1, short, short><<<NN1/32, 256, 0, stream>>>(
            xbf, FIN, nid, ptq1, bq1 + r*HC1, q1b, pts1, bs1 + r*HC1, xr1);

        // ---- layer 1 fused attention + epilogue ----
        attn1_k<<<NN1, 64, 0, stream>>>(offs1 + (size_t)r*(NN1+1), slist1 + (size_t)r*NE1,
            q1b, k1b, v1b, xr1,
            wbeta1 + (size_t)r*3*HC1,
            bn_g + (size_t)r*HC1, bn_b + (size_t)r*HC1,
            bn_m + (size_t)r*HC1, bn_v + (size_t)r*HC1, hbf);

        // ---- layer 2 projections (MFMA; K fp8, V bf16) ----
        gemm2l<HC1, HC2, unsigned char, short><<<NN1/32, 256, 0, stream>>>(
            hbf, HC1, nullptr, ptk2, bk2 + r*HC2, k2b, ptv2, bv2 + r*HC2, v2b);
        gemm2l<HC1, HC2, short, short><<<NB/32, 256, 0, stream>>>(
            hbf, HC1, nullptr, ptq2, bq2 + r*HC2, q2b, pts2, bs2 + r*HC2, xr2);

        // ---- layer 2 fused attention + output ----
        attn2_k<<<NB, 64, 0, stream>>>(offs2 + (size_t)r*(NB+1), slist2 + (size_t)r*NE2,
            q2b, k2b, v2b, xr2,
            wbeta2 + (size_t)r*3*HC2, outp, r*HC2);
    }
}

// Round 14
// 516.767 us; speedup vs baseline: 1.0536x; 1.0536x over previous
//
#include <hip/hip_runtime.h>
#include <math.h>

#define RR 3
#define NTOT 100000
#define NN0 80000
#define NN1 20000
#define NB 4096
#define NE1 300000
#define NE2 65536
#define FIN 128
#define HC1 256   // layer1: 2 heads x 128
#define HC2 128   // layer2: 1 head x 128

typedef __attribute__((ext_vector_type(8))) short bf16x8;
typedef __attribute__((ext_vector_type(4))) short s16x4;
typedef __attribute__((ext_vector_type(2))) short s16x2;
typedef __attribute__((ext_vector_type(4))) float f32x4;
typedef __attribute__((ext_vector_type(2))) float f32x2;

__device__ __forceinline__ float wave_red_sum(float v) {
    #pragma unroll
    for (int off = 32; off >= 1; off >>= 1) v += __shfl_xor(v, off, 64);
    return v;
}

__device__ __forceinline__ short f2bf(float x) {
    union { float f; unsigned u; } c; c.f = x;
    unsigned r = c.u + 0x7fffu + ((c.u >> 16) & 1u);
    return (short)(r >> 16);
}
__device__ __forceinline__ float bf2f(short s) {
    union { unsigned u; float f; } c; c.u = ((unsigned)(unsigned short)s) << 16;
    return c.f;
}

// fp8 e4m3 (OCP) HW converters
__device__ __forceinline__ float4 dec_fp8x4(unsigned w) {
    f32x2 lo = __builtin_amdgcn_cvt_pk_f32_fp8((int)w, false);
    f32x2 hi = __builtin_amdgcn_cvt_pk_f32_fp8((int)w, true);
    float4 r = { lo[0], lo[1], hi[0], hi[1] };
    return r;
}
__device__ __forceinline__ float2 dec_fp8x2(unsigned w) {
    f32x2 lo = __builtin_amdgcn_cvt_pk_f32_fp8((int)w, false);
    float2 r = { lo[0], lo[1] };
    return r;
}
__device__ __forceinline__ unsigned enc_fp8x4(float a, float b, float c, float d) {
    int w = __builtin_amdgcn_cvt_pk_fp8_f32(a, b, 0, false);
    w = __builtin_amdgcn_cvt_pk_fp8_f32(c, d, w, true);
    return (unsigned)w;
}

__device__ __forceinline__ float4 ld4(const float* p) { return *(const float4*)p; }
__device__ __forceinline__ float4 ld4(const short* p) {
    s16x4 v = *(const s16x4*)p;
    float4 r = { bf2f(v[0]), bf2f(v[1]), bf2f(v[2]), bf2f(v[3]) };
    return r;
}
__device__ __forceinline__ float2 ld2(const float* p) { return *(const float2*)p; }
__device__ __forceinline__ float2 ld2(const short* p) {
    s16x2 v = *(const s16x2*)p;
    float2 r = { bf2f(v[0]), bf2f(v[1]) };
    return r;
}

// ---------- convert features f32 -> bf16 ----------
__global__ void __launch_bounds__(256)
fcvt_k(const float* __restrict__ f, short* __restrict__ o, int n4) {
    int i = blockIdx.x * 256 + threadIdx.x;
    if (i < n4) {
        float4 v = *(const float4*)(f + (size_t)i * 4);
        s16x4 s = { f2bf(v.x), f2bf(v.y), f2bf(v.z), f2bf(v.w) };
        *(s16x4*)(o + (size_t)i * 4) = s;
    }
}

// ---------- pack 4 weight mats per replica into MFMA B-fragment order ----------
template<int K, int N>
__global__ void __launch_bounds__(256)
wpack_k(const float* __restrict__ W0, const float* __restrict__ W1,
        const float* __restrict__ W2, const float* __restrict__ W3,
        short* __restrict__ P) {
    constexpr int KS = K / 32;
    const int m = blockIdx.y, r = blockIdx.z;
    const float* W = (m == 0 ? W0 : m == 1 ? W1 : m == 2 ? W2 : W3) + (size_t)r * K * N;
    short* o = P + ((size_t)(r * 4 + m)) * K * N;
    for (int i = blockIdx.x * 256 + threadIdx.x; i < K * N; i += gridDim.x * 256) {
        int j = i & 7, lane = (i >> 3) & 63, f = i >> 9;
        int ks = f % KS, nt = f / KS;
        int k = ks * 32 + (lane >> 4) * 8 + j;
        int n = nt * 16 + (lane & 15);
        o[i] = f2bf(W[(size_t)k * N + n]);
    }
}

// ---------- MFMA GEMM, low-pressure tiling ----------
// OT: float=f32, short=bf16, unsigned char=fp8(e4m3)
template<int K, int N, typename OT0, typename OT1>
__global__ void __launch_bounds__(256)
gemm2l(const short* __restrict__ xbf, int ldx, const int* __restrict__ gidx,
       const short* __restrict__ P0, const float* __restrict__ b0, OT0* __restrict__ out0,
       const short* __restrict__ P1, const float* __restrict__ b1, OT1* __restrict__ out1)
{
    constexpr int NT = N / 16;
    constexpr int NW = NT / 4;
    constexpr int KS = K / 32;
    constexpr int MT = 2;
    const int lane = threadIdx.x & 63;
    const int wid  = threadIdx.x >> 6;
    const int rowbase = blockIdx.x * (MT * 16);

    const short* ap[MT];
    #pragma unroll
    for (int mt = 0; mt < MT; ++mt) {
        int arow = rowbase + mt * 16 + (lane & 15);
        int srow = gidx ? gidx[arow] : arow;
        ap[mt] = xbf + (size_t)srow * ldx + ((lane >> 4) * 8);
    }
    const int fb = lane * 8;

    f32x4 acc[MT][NW][2];
    #pragma unroll
    for (int mt = 0; mt < MT; ++mt)
        #pragma unroll
        for (int j = 0; j < NW; ++j) { acc[mt][j][0] = (f32x4)(0.0f); acc[mt][j][1] = (f32x4)(0.0f); }

    for (int ks = 0; ks < KS; ++ks) {
        bf16x8 a[MT];
        #pragma unroll
        for (int mt = 0; mt < MT; ++mt) a[mt] = *(const bf16x8*)(ap[mt] + ks * 32);
        #pragma unroll
        for (int j = 0; j < NW; ++j) {
            const int nt = wid * NW + j;
            const int off = ((nt * KS + ks) << 9) + fb;
            bf16x8 bv0 = *(const bf16x8*)(P0 + off);
            bf16x8 bv1 = *(const bf16x8*)(P1 + off);
            #pragma unroll
            for (int mt = 0; mt < MT; ++mt) {
                acc[mt][j][0] = __builtin_amdgcn_mfma_f32_16x16x32_bf16(a[mt], bv0, acc[mt][j][0], 0, 0, 0);
                acc[mt][j][1] = __builtin_amdgcn_mfma_f32_16x16x32_bf16(a[mt], bv1, acc[mt][j][1], 0, 0, 0);
            }
        }
    }

    __shared__ float ls[MT * 16][N + 4];
    constexpr int CPT = (MT * 16) * N / 8 / 256;
    const int tid = threadIdx.x;

    #pragma unroll
    for (int mat = 0; mat < 2; ++mat) {
        if (mat) __syncthreads();
        const float* bias = mat ? b1 : b0;
        #pragma unroll
        for (int j = 0; j < NW; ++j) {
            const int nt = wid * NW + j;
            const float bb = bias[nt * 16 + (lane & 15)];
            #pragma unroll
            for (int mt = 0; mt < MT; ++mt)
                #pragma unroll
                for (int rg = 0; rg < 4; ++rg)
                    ls[mt * 16 + (lane >> 4) * 4 + rg][nt * 16 + (lane & 15)] =
                        acc[mt][j][mat][rg] + bb;
        }
        __syncthreads();
        #pragma unroll
        for (int c2 = 0; c2 < CPT; ++c2) {
            const int chunk = c2 * 256 + tid;
            const int row = chunk / (N / 8);
            const int colb = (chunk % (N / 8)) * 8;
            float v[8];
            #pragma unroll
            for (int i = 0; i < 8; ++i) v[i] = ls[row][colb + i];
            const size_t gbase = (size_t)(rowbase + row) * N + colb;
            if (mat == 0) {
                if constexpr (sizeof(OT0) == 1) {
                    uint2 u = { enc_fp8x4(v[0],v[1],v[2],v[3]), enc_fp8x4(v[4],v[5],v[6],v[7]) };
                    *(uint2*)((unsigned char*)out0 + gbase) = u;
                } else if constexpr (sizeof(OT0) == 2) {
                    bf16x8 s;
                    #pragma unroll
                    for (int i = 0; i < 8; ++i) s[i] = f2bf(v[i]);
                    *(bf16x8*)(out0 + gbase) = s;
                } else {
                    float4 lo = { v[0], v[1], v[2], v[3] }, hi = { v[4], v[5], v[6], v[7] };
                    *(float4*)(out0 + gbase) = lo;
                    *(float4*)(out0 + gbase + 4) = hi;
                }
            } else {
                if constexpr (sizeof(OT1) == 1) {
                    uint2 u = { enc_fp8x4(v[0],v[1],v[2],v[3]), enc_fp8x4(v[4],v[5],v[6],v[7]) };
                    *(uint2*)((unsigned char*)out1 + gbase) = u;
                } else if constexpr (sizeof(OT1) == 2) {
                    bf16x8 s;
                    #pragma unroll
                    for (int i = 0; i < 8; ++i) s[i] = f2bf(v[i]);
                    *(bf16x8*)(out1 + gbase) = s;
                } else {
                    float4 lo = { v[0], v[1], v[2], v[3] }, hi = { v[4], v[5], v[6], v[7] };
                    *(float4*)(out1 + gbase) = lo;
                    *(float4*)(out1 + gbase + 4) = hi;
                }
            }
        }
    }
}

// ================= two-level CSR build (round-11, known-good) =================
template<int TS>
__global__ void __launch_bounds__(256)
csr_a1(const int* __restrict__ ei, int E, int R, int T, int* __restrict__ cnt_tr) {
    const int r = blockIdx.y, tile = blockIdx.x;
    const int* dst = ei + (size_t)r * 2 * E + E;
    __shared__ int h[64];
    for (int i = threadIdx.x; i < R; i += 256) h[i] = 0;
    __syncthreads();
    const int e0 = tile * TS, e1 = min(e0 + TS, E);
    for (int e = e0 + threadIdx.x; e < e1; e += 256) atomicAdd(&h[dst[e] >> 9], 1);
    __syncthreads();
    for (int i = threadIdx.x; i < R; i += 256)
        cnt_tr[((size_t)r * R + i) * T + tile] = h[i];
}
__global__ void __launch_bounds__(64)
csr_b(const int* __restrict__ cnt_tr, int R, int T, int E, int nbins,
      int* __restrict__ base_tr, int* __restrict__ rbase, int* __restrict__ offsg) {
    const int r = blockIdx.x;
    __shared__ int tot[64];
    const int t = threadIdx.x;
    if (t < R) {
        const int* c = cnt_tr + ((size_t)r * R + t) * T;
        int s = 0;
        for (int i = 0; i < T; ++i) s += c[i];
        tot[t] = s;
    }
    __syncthreads();
    if (t == 0) { int run = 0; for (int i = 0; i < R; ++i) { int c = tot[i]; tot[i] = run; run += c; } }
    __syncthreads();
    if (t < R) {
        const int* c = cnt_tr + ((size_t)r * R + t) * T;
        int* b = base_tr + ((size_t)r * R + t) * T;
        int run = tot[t];
        for (int i = 0; i < T; ++i) { b[i] = run; run += c[i]; }
        rbase[(size_t)r * (R + 1) + t] = tot[t];
    }
    if (t == 0) {
        rbase[(size_t)r * (R + 1) + R] = E;
        offsg[(size_t)r * (nbins + 1) + nbins] = E;
    }
}
template<int TS>
__global__ void __launch_bounds__(256)
csr_a2(const int* __restrict__ ei, int E, int R, int T,
       const int* __restrict__ base_tr, unsigned long long* __restrict__ scratch) {
    const int r = blockIdx.y, tile = blockIdx.x;
    const int* src = ei + (size_t)r * 2 * E;
    const int* dst = src + E;
    __shared__ int cur[64];
    for (int i = threadIdx.x; i < R; i += 256)
        cur[i] = base_tr[((size_t)r * R + i) * T + tile];
    __syncthreads();
    unsigned long long* sc = scratch + (size_t)r * E;
    const int e0 = tile * TS, e1 = min(e0 + TS, E);
    for (int e = e0 + threadIdx.x; e < e1; e += 256) {
        int d = dst[e];
        int pos = atomicAdd(&cur[d >> 9], 1);
        sc[pos] = ((unsigned long long)(unsigned)d << 32) | (unsigned)src[e];
    }
}
__global__ void __launch_bounds__(256)
csr_c(const unsigned long long* __restrict__ scratch, const int* __restrict__ rbase,
      int E, int R, int nbins, int* __restrict__ offsg, int* __restrict__ slistg) {
    const int r = blockIdx.y, range = blockIdx.x;
    const unsigned long long* sc = scratch + (size_t)r * E;
    const int* rb = rbase + (size_t)r * (R + 1);
    int* offs = offsg + (size_t)r * (nbins + 1);
    int* slist = slistg + (size_t)r * E;
    const int s0 = rb[range], s1 = rb[range + 1];
    const int lo = range << 9;
    const int nb = min(512, nbins - lo);
    __shared__ int h0[512];
    __shared__ int cur[512];
    __shared__ int ps[256];
    const int tid = threadIdx.x;
    h0[2*tid] = 0; h0[2*tid+1] = 0;
    __syncthreads();
    for (int i = s0 + tid; i < s1; i += 256)
        atomicAdd(&h0[(int)(sc[i] >> 32) - lo], 1);
    __syncthreads();
    const int a_ = h0[2*tid], b_ = h0[2*tid+1];
    ps[tid] = a_ + b_;
    __syncthreads();
    for (int off = 1; off < 256; off <<= 1) {
        int v = (tid >= off) ? ps[tid - off] : 0;
        __syncthreads();
        ps[tid] += v;
        __syncthreads();
    }
    const int base = (tid ? ps[tid - 1] : 0) + s0;
    const int o0 = base, o1 = base + a_;
    if (2*tid     < nb) offs[lo + 2*tid]     = o0;
    if (2*tid + 1 < nb) offs[lo + 2*tid + 1] = o1;
    cur[2*tid] = o0; cur[2*tid+1] = o1;
    __syncthreads();
    for (int i = s0 + tid; i < s1; i += 256) {
        unsigned long long v = sc[i];
        int d = (int)(v >> 32) - lo;
        int pos = atomicAdd(&cur[d], 1);
        slist[pos] = (int)(v & 0xffffffffu);
    }
}

// ---------- fused layer-1 attention, edge-PAIR pipelined; K fp8, V bf16 ----------
__global__ void __launch_bounds__(64)
attn1_k(const int* __restrict__ offs, const int* __restrict__ slist,
        const short* __restrict__ qb, const unsigned char* __restrict__ kb,
        const short* __restrict__ vb,
        const short* __restrict__ xr, const float* __restrict__ wb,
        const float* __restrict__ g, const float* __restrict__ bbn,
        const float* __restrict__ mean, const float* __restrict__ var,
        short* __restrict__ hb)
{
    const int n = blockIdx.x;
    const int lane = threadIdx.x;
    const int c0 = lane * 4;
    const int lo = offs[n], hi = offs[n+1];
    const float4 q = ld4(qb + (size_t)n * HC1 + c0);
    const float scale = 0.088388347648318447f;   // 1/sqrt(128)

    float m = -INFINITY, s = 0.f;
    float a0 = 0.f, a1 = 0.f, a2 = 0.f, a3 = 0.f;
    unsigned kw0 = 0, kw1 = 0;
    float4 v0 = {0,0,0,0}, v1 = {0,0,0,0};
    if (lo < hi) {
        int sr = slist[lo];
        kw0 = *(const unsigned*)(kb + (size_t)sr * HC1 + c0);
        v0 = ld4(vb + (size_t)sr * HC1 + c0);
    }
    if (lo + 1 < hi) {
        int sr = slist[lo + 1];
        kw1 = *(const unsigned*)(kb + (size_t)sr * HC1 + c0);
        v1 = ld4(vb + (size_t)sr * HC1 + c0);
    }
    for (int i = lo; i < hi; i += 2) {
        unsigned kwn0 = 0, kwn1 = 0;
        float4 vn0 = {0,0,0,0}, vn1 = {0,0,0,0};
        if (i + 2 < hi) {
            int sr = slist[i + 2];
            kwn0 = *(const unsigned*)(kb + (size_t)sr * HC1 + c0);
            vn0 = ld4(vb + (size_t)sr * HC1 + c0);
        }
        if (i + 3 < hi) {
            int sr = slist[i + 3];
            kwn1 = *(const unsigned*)(kb + (size_t)sr * HC1 + c0);
            vn1 = ld4(vb + (size_t)sr * HC1 + c0);
        }
        const float4 k0 = dec_fp8x4(kw0);
        const float4 k1 = dec_fp8x4(kw1);
        float p0 = q.x*k0.x + q.y*k0.y + q.z*k0.z + q.w*k0.w;
        float p1 = q.x*k1.x + q.y*k1.y + q.z*k1.z + q.w*k1.w;
        #pragma unroll
        for (int off = 16; off >= 1; off >>= 1) {
            p0 += __shfl_xor(p0, off, 64);
            p1 += __shfl_xor(p1, off, 64);
        }
        const float alpha0 = p0 * scale;
        const float alpha1 = (i + 1 < hi) ? p1 * scale : -INFINITY;
        float mn = fmaxf(m, alpha0);
        float rs = __expf(m - mn);
        float pp = __expf(alpha0 - mn);
        s  = s*rs + pp;
        a0 = a0*rs + pp*v0.x; a1 = a1*rs + pp*v0.y;
        a2 = a2*rs + pp*v0.z; a3 = a3*rs + pp*v0.w;
        m = mn;
        mn = fmaxf(m, alpha1);
        rs = __expf(m - mn);
        pp = __expf(alpha1 - mn);
        s  = s*rs + pp;
        a0 = a0*rs + pp*v1.x; a1 = a1*rs + pp*v1.y;
        a2 = a2*rs + pp*v1.z; a3 = a3*rs + pp*v1.w;
        m = mn;
        kw0 = kwn0; v0 = vn0; kw1 = kwn1; v1 = vn1;
    }
    const float inv = (s > 0.f) ? 1.f/s : 0.f;
    const float att[4] = { a0*inv, a1*inv, a2*inv, a3*inv };

    const float4 x4 = ld4(xr + (size_t)n * HC1 + c0);
    const float xx[4] = { x4.x, x4.y, x4.z, x4.w };
    float d = 0.f;
    #pragma unroll
    for (int j = 0; j < 4; ++j) {
        int c = c0 + j;
        d += att[j]*wb[c] + xx[j]*wb[HC1 + c] + (att[j]-xx[j])*wb[2*HC1 + c];
    }
    d = wave_red_sum(d);
    const float beta = 1.f / (1.f + __expf(-d));
    s16x4 hv4;
    #pragma unroll
    for (int j = 0; j < 4; ++j) {
        int c = c0 + j;
        float hv = beta*xx[j] + (1.f-beta)*att[j];
        hv = (hv - mean[c]) * rsqrtf(var[c] + 1e-5f) * g[c] + bbn[c];
        hv = hv > 0.f ? hv : expm1f(hv);
        hv4[j] = f2bf(hv);
    }
    *(s16x4*)(hb + (size_t)n * HC1 + c0) = hv4;
}

// ---------- fused layer-2 attention, edge-PAIR pipelined; K fp8, V bf16 ----------
__global__ void __launch_bounds__(64)
attn2_k(const int* __restrict__ offs, const int* __restrict__ slist,
        const short* __restrict__ qb, const unsigned char* __restrict__ kb,
        const short* __restrict__ vb,
        const short* __restrict__ xr, const float* __restrict__ wb,
        float* __restrict__ outp, int colofs)
{
    const int n = blockIdx.x;
    const int lane = threadIdx.x;
    const int c0 = lane * 2;
    const int lo = offs[n], hi = offs[n+1];
    const float2 q = ld2(qb + (size_t)n * HC2 + c0);
    const float scale = 0.088388347648318447f;   // 1/sqrt(128)

    float m = -INFINITY, s = 0.f;
    float a0 = 0.f, a1 = 0.f;
    unsigned kw0 = 0, kw1 = 0;
    float2 v0 = {0,0}, v1 = {0,0};
    if (lo < hi) {
        int sr = slist[lo];
        kw0 = *(const unsigned short*)(kb + (size_t)sr * HC2 + c0);
        v0 = ld2(vb + (size_t)sr * HC2 + c0);
    }
    if (lo + 1 < hi) {
        int sr = slist[lo + 1];
        kw1 = *(const unsigned short*)(kb + (size_t)sr * HC2 + c0);
        v1 = ld2(vb + (size_t)sr * HC2 + c0);
    }
    for (int i = lo; i < hi; i += 2) {
        unsigned kwn0 = 0, kwn1 = 0;
        float2 vn0 = {0,0}, vn1 = {0,0};
        if (i + 2 < hi) {
            int sr = slist[i + 2];
            kwn0 = *(const unsigned short*)(kb + (size_t)sr * HC2 + c0);
            vn0 = ld2(vb + (size_t)sr * HC2 + c0);
        }
        if (i + 3 < hi) {
            int sr = slist[i + 3];
            kwn1 = *(const unsigned short*)(kb + (size_t)sr * HC2 + c0);
            vn1 = ld2(vb + (size_t)sr * HC2 + c0);
        }
        const float2 k0 = dec_fp8x2(kw0);
        const float2 k1 = dec_fp8x2(kw1);
        float p0 = q.x*k0.x + q.y*k0.y;
        float p1 = q.x*k1.x + q.y*k1.y;
        #pragma unroll
        for (int off = 32; off >= 1; off >>= 1) {
            p0 += __shfl_xor(p0, off, 64);
            p1 += __shfl_xor(p1, off, 64);
        }
        const float alpha0 = p0 * scale;
        const float alpha1 = (i + 1 < hi) ? p1 * scale : -INFINITY;
        float mn = fmaxf(m, alpha0);
        float rs = __expf(m - mn);
        float pp = __expf(alpha0 - mn);
        s  = s*rs + pp;
        a0 = a0*rs + pp*v0.x; a1 = a1*rs + pp*v0.y;
        m = mn;
        mn = fmaxf(m, alpha1);
        rs = __expf(m - mn);
        pp = __expf(alpha1 - mn);
        s  = s*rs + pp;
        a0 = a0*rs + pp*v1.x; a1 = a1*rs + pp*v1.y;
        m = mn;
        kw0 = kwn0; v0 = vn0; kw1 = kwn1; v1 = vn1;
    }
    const float inv = (s > 0.f) ? 1.f/s : 0.f;
    const float att0 = a0*inv, att1 = a1*inv;

    const float2 x2 = ld2(xr + (size_t)n * HC2 + c0);
    float d = att0*wb[c0] + att1*wb[c0+1]
            + x2.x*wb[HC2+c0] + x2.y*wb[HC2+c0+1]
            + (att0-x2.x)*wb[2*HC2+c0] + (att1-x2.y)*wb[2*HC2+c0+1];
    d = wave_red_sum(d);
    const float beta = 1.f/(1.f+__expf(-d));
    outp[(size_t)n*(RR*HC2) + colofs + c0]     = beta*x2.x + (1.f-beta)*att0;
    outp[(size_t)n*(RR*HC2) + colofs + c0 + 1] = beta*x2.y + (1.f-beta)*att1;
}

extern "C" void kernel_launch(void* const* d_in, const int* in_sizes, int n_in,
                              void* d_out, int out_size, void* d_ws, size_t ws_size,
                              hipStream_t stream)
{
    const float* features = (const float*)d_in[0];
    const int*   n_ids    = (const int*)d_in[1];
    const int*   ei1      = (const int*)d_in[2];
    const int*   ei2      = (const int*)d_in[3];
    const float* wq1 = (const float*)d_in[4];  const float* bq1 = (const float*)d_in[5];
    const float* wk1 = (const float*)d_in[6];  const float* bk1 = (const float*)d_in[7];
    const float* wv1 = (const float*)d_in[8];  const float* bv1 = (const float*)d_in[9];
    const float* ws1 = (const float*)d_in[10]; const float* bs1 = (const float*)d_in[11];
    const float* wbeta1 = (const float*)d_in[12];
    const float* bn_g = (const float*)d_in[13]; const float* bn_b = (const float*)d_in[14];
    const float* bn_m = (const float*)d_in[15]; const float* bn_v = (const float*)d_in[16];
    const float* wq2 = (const float*)d_in[17]; const float* bq2 = (const float*)d_in[18];
    const float* wk2 = (const float*)d_in[19]; const float* bk2 = (const float*)d_in[20];
    const float* wv2 = (const float*)d_in[21]; const float* bv2 = (const float*)d_in[22];
    const float* ws2 = (const float*)d_in[23]; const float* bs2 = (const float*)d_in[24];
    const float* wbeta2 = (const float*)d_in[25];
    float* outp = (float*)d_out;

    // CSR build geometry
    constexpr int TS = 8192;
    constexpr int T1 = (NE1 + TS - 1) / TS;   // 37
    constexpr int T2 = (NE2 + TS - 1) / TS;   // 8
    constexpr int R1 = (NN1 + 511) >> 9;      // 40
    constexpr int R2 = (NB  + 511) >> 9;      // 8

    char* p = (char*)d_ws;
    auto alloc = [&](size_t bytes) { char* q = p; p += (bytes + 255) & ~(size_t)255; return q; };
    unsigned char* k1b = (unsigned char*)alloc((size_t)NN0*HC1);     // 20.5 MB fp8
    short* v1b  = (short*)alloc(sizeof(short)*(size_t)NN0*HC1);      // 41 MB bf16
    short* q1b  = (short*)alloc(sizeof(short)*(size_t)NN1*HC1);
    short* xr1  = (short*)alloc(sizeof(short)*(size_t)NN1*HC1);      // bf16
    short* hbf  = (short*)alloc(sizeof(short)*(size_t)NN1*HC1);
    short* xbf  = (short*)alloc(sizeof(short)*(size_t)NTOT*FIN);
    short* wt1  = (short*)alloc(sizeof(short)*(size_t)RR*4*FIN*HC1);
    short* wt2  = (short*)alloc(sizeof(short)*(size_t)RR*4*HC1*HC2);
    unsigned char* k2b = (unsigned char*)alloc((size_t)NN1*HC2);     // fp8
    short* v2b  = (short*)alloc(sizeof(short)*(size_t)NN1*HC2);
    short* q2b  = (short*)alloc(sizeof(short)*(size_t)NB*HC2);
    short* xr2  = (short*)alloc(sizeof(short)*(size_t)NB*HC2);       // bf16
    // CSR state (all replicas)
    int* offs1  = (int*)alloc(sizeof(int)*(size_t)RR*(NN1+1));
    int* slist1 = (int*)alloc(sizeof(int)*(size_t)RR*NE1);
    int* offs2  = (int*)alloc(sizeof(int)*(size_t)RR*(NB+1));
    int* slist2 = (int*)alloc(sizeof(int)*(size_t)RR*NE2);
    unsigned long long* scr1 = (unsigned long long*)alloc(sizeof(unsigned long long)*(size_t)RR*NE1);
    unsigned long long* scr2 = (unsigned long long*)alloc(sizeof(unsigned long long)*(size_t)RR*NE2);
    int* cnt_tr1  = (int*)alloc(sizeof(int)*(size_t)RR*R1*T1);
    int* base_tr1 = (int*)alloc(sizeof(int)*(size_t)RR*R1*T1);
    int* rbase1   = (int*)alloc(sizeof(int)*(size_t)RR*(R1+1));
    int* cnt_tr2  = (int*)alloc(sizeof(int)*(size_t)RR*R2*T2);
    int* base_tr2 = (int*)alloc(sizeof(int)*(size_t)RR*R2*T2);
    int* rbase2   = (int*)alloc(sizeof(int)*(size_t)RR*(R2+1));
    (void)ws_size; (void)in_sizes; (void)n_in; (void)out_size;

    // ---- prologue: conversions + weight packing ----
    fcvt_k<<<(NTOT*FIN/4 + 255)/256, 256, 0, stream>>>(features, xbf, NTOT*FIN/4);
    {
        dim3 g1(128, 4, RR);
        wpack_k<FIN, HC1><<<g1, 256, 0, stream>>>(wq1, wk1, wv1, ws1, wt1);
        dim3 g2(128, 4, RR);
        wpack_k<HC1, HC2><<<g2, 256, 0, stream>>>(wq2, wk2, wv2, ws2, wt2);
    }

    // ---- two-level CSR builds ----
    {
        dim3 ga1(T1, RR), ga2(T2, RR);
        csr_a1<TS><<<ga1, 256, 0, stream>>>(ei1, NE1, R1, T1, cnt_tr1);
        csr_a1<TS><<<ga2, 256, 0, stream>>>(ei2, NE2, R2, T2, cnt_tr2);
        csr_b<<<RR, 64, 0, stream>>>(cnt_tr1, R1, T1, NE1, NN1, base_tr1, rbase1, offs1);
        csr_b<<<RR, 64, 0, stream>>>(cnt_tr2, R2, T2, NE2, NB,  base_tr2, rbase2, offs2);
        csr_a2<TS><<<ga1, 256, 0, stream>>>(ei1, NE1, R1, T1, base_tr1, scr1);
        csr_a2<TS><<<ga2, 256, 0, stream>>>(ei2, NE2, R2, T2, base_tr2, scr2);
        dim3 gc1(R1, RR), gc2(R2, RR);
        csr_c<<<gc1, 256, 0, stream>>>(scr1, rbase1, NE1, R1, NN1, offs1, slist1);
        csr_c<<<gc2, 256, 0, stream>>>(scr2, rbase2, NE2, R2, NB,  offs2, slist2);
    }

    const size_t WSZ = (size_t)FIN*HC1;

    for (int r = 0; r < RR; ++r) {
        const int* nid  = n_ids + (size_t)r*NN0;
        const short* ptq1 = wt1 + ((size_t)r*4 + 0)*WSZ;
        const short* ptk1 = wt1 + ((size_t)r*4 + 1)*WSZ;
        const short* ptv1 = wt1 + ((size_t)r*4 + 2)*WSZ;
        const short* pts1 = wt1 + ((size_t)r*4 + 3)*WSZ;
        const short* ptq2 = wt2 + ((size_t)r*4 + 0)*WSZ;
        const short* ptk2 = wt2 + ((size_t)r*4 + 1)*WSZ;
        const short* ptv2 = wt2 + ((size_t)r*4 + 2)*WSZ;
        const short* pts2 = wt2 + ((size_t)r*4 + 3)*WSZ;

        // ---- layer 1 projections (MFMA, fused gather; K fp8, V bf16) ----
        gemm2l<FIN, HC1, unsigned char, short><<<NN0/32, 256, 0, stream>>>(
            xbf, FIN, nid, ptk1, bk1 + r*HC1, k1b, ptv1, bv1 + r*HC1, v1b);
        gemm2l<FIN, HC1, short, short><<<NN1/32, 256, 0, stream>>>(
            xbf, FIN, nid, ptq1, bq1 + r*HC1, q1b, pts1, bs1 + r*HC1, xr1);

        // ---- layer 1 fused attention + epilogue ----
        attn1_k<<<NN1, 64, 0, stream>>>(offs1 + (size_t)r*(NN1+1), slist1 + (size_t)r*NE1,
            q1b, k1b, v1b, xr1,
            wbeta1 + (size_t)r*3*HC1,
            bn_g + (size_t)r*HC1, bn_b + (size_t)r*HC1,
            bn_m + (size_t)r*HC1, bn_v + (size_t)r*HC1, hbf);

        // ---- layer 2 projections (MFMA; K fp8, V bf16) ----
        gemm2l<HC1, HC2, unsigned char, short><<<NN1/32, 256, 0, stream>>>(
            hbf, HC1, nullptr, ptk2, bk2 + r*HC2, k2b, ptv2, bv2 + r*HC2, v2b);
        gemm2l<HC1, HC2, short, short><<<NB/32, 256, 0, stream>>>(
            hbf, HC1, nullptr, ptq2, bq2 + r*HC2, q2b, pts2, bs2 + r*HC2, xr2);

        // ---- layer 2 fused attention + output ----
        attn2_k<<<NB, 64, 0, stream>>>(offs2 + (size_t)r*(NB+1), slist2 + (size_t)r*NE2,
            q2b, k2b, v2b, xr2,
            wbeta2 + (size_t)r*3*HC2, outp, r*HC2);
    }
}

// Round 15
// 516.130 us; speedup vs baseline: 1.0549x; 1.0012x over previous
//
#include <hip/hip_runtime.h>
#include <math.h>

#define RR 3
#define NTOT 100000
#define NN0 80000
#define NN1 20000
#define NB 4096
#define NE1 300000
#define NE2 65536
#define FIN 128
#define HC1 256   // layer1: 2 heads x 128
#define HC2 128   // layer2: 1 head x 128

typedef __attribute__((ext_vector_type(8))) short bf16x8;
typedef __attribute__((ext_vector_type(4))) short s16x4;
typedef __attribute__((ext_vector_type(2))) short s16x2;
typedef __attribute__((ext_vector_type(4))) float f32x4;
typedef __attribute__((ext_vector_type(2))) float f32x2;

__device__ __forceinline__ float wave_red_sum(float v) {
    #pragma unroll
    for (int off = 32; off >= 1; off >>= 1) v += __shfl_xor(v, off, 64);
    return v;
}

__device__ __forceinline__ short f2bf(float x) {
    union { float f; unsigned u; } c; c.f = x;
    unsigned r = c.u + 0x7fffu + ((c.u >> 16) & 1u);
    return (short)(r >> 16);
}
__device__ __forceinline__ float bf2f(short s) {
    union { unsigned u; float f; } c; c.u = ((unsigned)(unsigned short)s) << 16;
    return c.f;
}

// fp8 e4m3 (OCP) HW converters
__device__ __forceinline__ float4 dec_fp8x4(unsigned w) {
    f32x2 lo = __builtin_amdgcn_cvt_pk_f32_fp8((int)w, false);
    f32x2 hi = __builtin_amdgcn_cvt_pk_f32_fp8((int)w, true);
    float4 r = { lo[0], lo[1], hi[0], hi[1] };
    return r;
}
__device__ __forceinline__ float2 dec_fp8x2(unsigned w) {
    f32x2 lo = __builtin_amdgcn_cvt_pk_f32_fp8((int)w, false);
    float2 r = { lo[0], lo[1] };
    return r;
}
__device__ __forceinline__ unsigned enc_fp8x4(float a, float b, float c, float d) {
    int w = __builtin_amdgcn_cvt_pk_fp8_f32(a, b, 0, false);
    w = __builtin_amdgcn_cvt_pk_fp8_f32(c, d, w, true);
    return (unsigned)w;
}

__device__ __forceinline__ float4 ld4(const float* p) { return *(const float4*)p; }
__device__ __forceinline__ float4 ld4(const short* p) {
    s16x4 v = *(const s16x4*)p;
    float4 r = { bf2f(v[0]), bf2f(v[1]), bf2f(v[2]), bf2f(v[3]) };
    return r;
}
__device__ __forceinline__ float2 ld2(const float* p) { return *(const float2*)p; }
__device__ __forceinline__ float2 ld2(const short* p) {
    s16x2 v = *(const s16x2*)p;
    float2 r = { bf2f(v[0]), bf2f(v[1]) };
    return r;
}

// ---------- convert features f32 -> bf16 ----------
__global__ void __launch_bounds__(256)
fcvt_k(const float* __restrict__ f, short* __restrict__ o, int n4) {
    int i = blockIdx.x * 256 + threadIdx.x;
    if (i < n4) {
        float4 v = *(const float4*)(f + (size_t)i * 4);
        s16x4 s = { f2bf(v.x), f2bf(v.y), f2bf(v.z), f2bf(v.w) };
        *(s16x4*)(o + (size_t)i * 4) = s;
    }
}

// ---------- pack 4 weight mats per replica into MFMA B-fragment order ----------
template<int K, int N>
__global__ void __launch_bounds__(256)
wpack_k(const float* __restrict__ W0, const float* __restrict__ W1,
        const float* __restrict__ W2, const float* __restrict__ W3,
        short* __restrict__ P) {
    constexpr int KS = K / 32;
    const int m = blockIdx.y, r = blockIdx.z;
    const float* W = (m == 0 ? W0 : m == 1 ? W1 : m == 2 ? W2 : W3) + (size_t)r * K * N;
    short* o = P + ((size_t)(r * 4 + m)) * K * N;
    for (int i = blockIdx.x * 256 + threadIdx.x; i < K * N; i += gridDim.x * 256) {
        int j = i & 7, lane = (i >> 3) & 63, f = i >> 9;
        int ks = f % KS, nt = f / KS;
        int k = ks * 32 + (lane >> 4) * 8 + j;
        int n = nt * 16 + (lane & 15);
        o[i] = f2bf(W[(size_t)k * N + n]);
    }
}

// ---------- MFMA GEMM, low-pressure tiling ----------
// OT: float=f32, short=bf16, unsigned char=fp8(e4m3)
template<int K, int N, typename OT0, typename OT1>
__global__ void __launch_bounds__(256)
gemm2l(const short* __restrict__ xbf, int ldx, const int* __restrict__ gidx,
       const short* __restrict__ P0, const float* __restrict__ b0, OT0* __restrict__ out0,
       const short* __restrict__ P1, const float* __restrict__ b1, OT1* __restrict__ out1)
{
    constexpr int NT = N / 16;
    constexpr int NW = NT / 4;
    constexpr int KS = K / 32;
    constexpr int MT = 2;
    const int lane = threadIdx.x & 63;
    const int wid  = threadIdx.x >> 6;
    const int rowbase = blockIdx.x * (MT * 16);

    const short* ap[MT];
    #pragma unroll
    for (int mt = 0; mt < MT; ++mt) {
        int arow = rowbase + mt * 16 + (lane & 15);
        int srow = gidx ? gidx[arow] : arow;
        ap[mt] = xbf + (size_t)srow * ldx + ((lane >> 4) * 8);
    }
    const int fb = lane * 8;

    f32x4 acc[MT][NW][2];
    #pragma unroll
    for (int mt = 0; mt < MT; ++mt)
        #pragma unroll
        for (int j = 0; j < NW; ++j) { acc[mt][j][0] = (f32x4)(0.0f); acc[mt][j][1] = (f32x4)(0.0f); }

    for (int ks = 0; ks < KS; ++ks) {
        bf16x8 a[MT];
        #pragma unroll
        for (int mt = 0; mt < MT; ++mt) a[mt] = *(const bf16x8*)(ap[mt] + ks * 32);
        #pragma unroll
        for (int j = 0; j < NW; ++j) {
            const int nt = wid * NW + j;
            const int off = ((nt * KS + ks) << 9) + fb;
            bf16x8 bv0 = *(const bf16x8*)(P0 + off);
            bf16x8 bv1 = *(const bf16x8*)(P1 + off);
            #pragma unroll
            for (int mt = 0; mt < MT; ++mt) {
                acc[mt][j][0] = __builtin_amdgcn_mfma_f32_16x16x32_bf16(a[mt], bv0, acc[mt][j][0], 0, 0, 0);
                acc[mt][j][1] = __builtin_amdgcn_mfma_f32_16x16x32_bf16(a[mt], bv1, acc[mt][j][1], 0, 0, 0);
            }
        }
    }

    __shared__ float ls[MT * 16][N + 4];
    constexpr int CPT = (MT * 16) * N / 8 / 256;
    const int tid = threadIdx.x;

    #pragma unroll
    for (int mat = 0; mat < 2; ++mat) {
        if (mat) __syncthreads();
        const float* bias = mat ? b1 : b0;
        #pragma unroll
        for (int j = 0; j < NW; ++j) {
            const int nt = wid * NW + j;
            const float bb = bias[nt * 16 + (lane & 15)];
            #pragma unroll
            for (int mt = 0; mt < MT; ++mt)
                #pragma unroll
                for (int rg = 0; rg < 4; ++rg)
                    ls[mt * 16 + (lane >> 4) * 4 + rg][nt * 16 + (lane & 15)] =
                        acc[mt][j][mat][rg] + bb;
        }
        __syncthreads();
        #pragma unroll
        for (int c2 = 0; c2 < CPT; ++c2) {
            const int chunk = c2 * 256 + tid;
            const int row = chunk / (N / 8);
            const int colb = (chunk % (N / 8)) * 8;
            float v[8];
            #pragma unroll
            for (int i = 0; i < 8; ++i) v[i] = ls[row][colb + i];
            const size_t gbase = (size_t)(rowbase + row) * N + colb;
            if (mat == 0) {
                if constexpr (sizeof(OT0) == 1) {
                    uint2 u = { enc_fp8x4(v[0],v[1],v[2],v[3]), enc_fp8x4(v[4],v[5],v[6],v[7]) };
                    *(uint2*)((unsigned char*)out0 + gbase) = u;
                } else if constexpr (sizeof(OT0) == 2) {
                    bf16x8 s;
                    #pragma unroll
                    for (int i = 0; i < 8; ++i) s[i] = f2bf(v[i]);
                    *(bf16x8*)(out0 + gbase) = s;
                } else {
                    float4 lo = { v[0], v[1], v[2], v[3] }, hi = { v[4], v[5], v[6], v[7] };
                    *(float4*)(out0 + gbase) = lo;
                    *(float4*)(out0 + gbase + 4) = hi;
                }
            } else {
                if constexpr (sizeof(OT1) == 1) {
                    uint2 u = { enc_fp8x4(v[0],v[1],v[2],v[3]), enc_fp8x4(v[4],v[5],v[6],v[7]) };
                    *(uint2*)((unsigned char*)out1 + gbase) = u;
                } else if constexpr (sizeof(OT1) == 2) {
                    bf16x8 s;
                    #pragma unroll
                    for (int i = 0; i < 8; ++i) s[i] = f2bf(v[i]);
                    *(bf16x8*)(out1 + gbase) = s;
                } else {
                    float4 lo = { v[0], v[1], v[2], v[3] }, hi = { v[4], v[5], v[6], v[7] };
                    *(float4*)(out1 + gbase) = lo;
                    *(float4*)(out1 + gbase + 4) = hi;
                }
            }
        }
    }
}

// ================= two-level CSR build (round-11, known-good) =================
template<int TS>
__global__ void __launch_bounds__(256)
csr_a1(const int* __restrict__ ei, int E, int R, int T, int* __restrict__ cnt_tr) {
    const int r = blockIdx.y, tile = blockIdx.x;
    const int* dst = ei + (size_t)r * 2 * E + E;
    __shared__ int h[64];
    for (int i = threadIdx.x; i < R; i += 256) h[i] = 0;
    __syncthreads();
    const int e0 = tile * TS, e1 = min(e0 + TS, E);
    for (int e = e0 + threadIdx.x; e < e1; e += 256) atomicAdd(&h[dst[e] >> 9], 1);
    __syncthreads();
    for (int i = threadIdx.x; i < R; i += 256)
        cnt_tr[((size_t)r * R + i) * T + tile] = h[i];
}
__global__ void __launch_bounds__(64)
csr_b(const int* __restrict__ cnt_tr, int R, int T, int E, int nbins,
      int* __restrict__ base_tr, int* __restrict__ rbase, int* __restrict__ offsg) {
    const int r = blockIdx.x;
    __shared__ int tot[64];
    const int t = threadIdx.x;
    if (t < R) {
        const int* c = cnt_tr + ((size_t)r * R + t) * T;
        int s = 0;
        for (int i = 0; i < T; ++i) s += c[i];
        tot[t] = s;
    }
    __syncthreads();
    if (t == 0) { int run = 0; for (int i = 0; i < R; ++i) { int c = tot[i]; tot[i] = run; run += c; } }
    __syncthreads();
    if (t < R) {
        const int* c = cnt_tr + ((size_t)r * R + t) * T;
        int* b = base_tr + ((size_t)r * R + t) * T;
        int run = tot[t];
        for (int i = 0; i < T; ++i) { b[i] = run; run += c[i]; }
        rbase[(size_t)r * (R + 1) + t] = tot[t];
    }
    if (t == 0) {
        rbase[(size_t)r * (R + 1) + R] = E;
        offsg[(size_t)r * (nbins + 1) + nbins] = E;
    }
}
template<int TS>
__global__ void __launch_bounds__(256)
csr_a2(const int* __restrict__ ei, int E, int R, int T,
       const int* __restrict__ base_tr, unsigned long long* __restrict__ scratch) {
    const int r = blockIdx.y, tile = blockIdx.x;
    const int* src = ei + (size_t)r * 2 * E;
    const int* dst = src + E;
    __shared__ int cur[64];
    for (int i = threadIdx.x; i < R; i += 256)
        cur[i] = base_tr[((size_t)r * R + i) * T + tile];
    __syncthreads();
    unsigned long long* sc = scratch + (size_t)r * E;
    const int e0 = tile * TS, e1 = min(e0 + TS, E);
    for (int e = e0 + threadIdx.x; e < e1; e += 256) {
        int d = dst[e];
        int pos = atomicAdd(&cur[d >> 9], 1);
        sc[pos] = ((unsigned long long)(unsigned)d << 32) | (unsigned)src[e];
    }
}
__global__ void __launch_bounds__(256)
csr_c(const unsigned long long* __restrict__ scratch, const int* __restrict__ rbase,
      int E, int R, int nbins, int* __restrict__ offsg, int* __restrict__ slistg) {
    const int r = blockIdx.y, range = blockIdx.x;
    const unsigned long long* sc = scratch + (size_t)r * E;
    const int* rb = rbase + (size_t)r * (R + 1);
    int* offs = offsg + (size_t)r * (nbins + 1);
    int* slist = slistg + (size_t)r * E;
    const int s0 = rb[range], s1 = rb[range + 1];
    const int lo = range << 9;
    const int nb = min(512, nbins - lo);
    __shared__ int h0[512];
    __shared__ int cur[512];
    __shared__ int ps[256];
    const int tid = threadIdx.x;
    h0[2*tid] = 0; h0[2*tid+1] = 0;
    __syncthreads();
    for (int i = s0 + tid; i < s1; i += 256)
        atomicAdd(&h0[(int)(sc[i] >> 32) - lo], 1);
    __syncthreads();
    const int a_ = h0[2*tid], b_ = h0[2*tid+1];
    ps[tid] = a_ + b_;
    __syncthreads();
    for (int off = 1; off < 256; off <<= 1) {
        int v = (tid >= off) ? ps[tid - off] : 0;
        __syncthreads();
        ps[tid] += v;
        __syncthreads();
    }
    const int base = (tid ? ps[tid - 1] : 0) + s0;
    const int o0 = base, o1 = base + a_;
    if (2*tid     < nb) offs[lo + 2*tid]     = o0;
    if (2*tid + 1 < nb) offs[lo + 2*tid + 1] = o1;
    cur[2*tid] = o0; cur[2*tid+1] = o1;
    __syncthreads();
    for (int i = s0 + tid; i < s1; i += 256) {
        unsigned long long v = sc[i];
        int d = (int)(v >> 32) - lo;
        int pos = atomicAdd(&cur[d], 1);
        slist[pos] = (int)(v & 0xffffffffu);
    }
}

// ---------- fused layer-1 attention, edge-PAIR pipelined; K fp8, V bf16 ----------
__global__ void __launch_bounds__(64)
attn1_k(const int* __restrict__ offs, const int* __restrict__ slist,
        const short* __restrict__ qb, const unsigned char* __restrict__ kb,
        const short* __restrict__ vb,
        const short* __restrict__ xr, const float* __restrict__ wb,
        const float* __restrict__ g, const float* __restrict__ bbn,
        const float* __restrict__ mean, const float* __restrict__ var,
        short* __restrict__ hb)
{
    const int n = blockIdx.x;
    const int lane = threadIdx.x;
    const int c0 = lane * 4;
    const int lo = offs[n], hi = offs[n+1];
    const float4 q = ld4(qb + (size_t)n * HC1 + c0);
    const float scale = 0.088388347648318447f;   // 1/sqrt(128)

    float m = -INFINITY, s = 0.f;
    float a0 = 0.f, a1 = 0.f, a2 = 0.f, a3 = 0.f;
    unsigned kw0 = 0, kw1 = 0;
    float4 v0 = {0,0,0,0}, v1 = {0,0,0,0};
    if (lo < hi) {
        int sr = slist[lo];
        kw0 = *(const unsigned*)(kb + (size_t)sr * HC1 + c0);
        v0 = ld4(vb + (size_t)sr * HC1 + c0);
    }
    if (lo + 1 < hi) {
        int sr = slist[lo + 1];
        kw1 = *(const unsigned*)(kb + (size_t)sr * HC1 + c0);
        v1 = ld4(vb + (size_t)sr * HC1 + c0);
    }
    for (int i = lo; i < hi; i += 2) {
        unsigned kwn0 = 0, kwn1 = 0;
        float4 vn0 = {0,0,0,0}, vn1 = {0,0,0,0};
        if (i + 2 < hi) {
            int sr = slist[i + 2];
            kwn0 = *(const unsigned*)(kb + (size_t)sr * HC1 + c0);
            vn0 = ld4(vb + (size_t)sr * HC1 + c0);
        }
        if (i + 3 < hi) {
            int sr = slist[i + 3];
            kwn1 = *(const unsigned*)(kb + (size_t)sr * HC1 + c0);
            vn1 = ld4(vb + (size_t)sr * HC1 + c0);
        }
        const float4 k0 = dec_fp8x4(kw0);
        const float4 k1 = dec_fp8x4(kw1);
        float p0 = q.x*k0.x + q.y*k0.y + q.z*k0.z + q.w*k0.w;
        float p1 = q.x*k1.x + q.y*k1.y + q.z*k1.z + q.w*k1.w;
        #pragma unroll
        for (int off = 16; off >= 1; off >>= 1) {
            p0 += __shfl_xor(p0, off, 64);
            p1 += __shfl_xor(p1, off, 64);
        }
        const float alpha0 = p0 * scale;
        const float alpha1 = (i + 1 < hi) ? p1 * scale : -INFINITY;
        float mn = fmaxf(m, alpha0);
        float rs = __expf(m - mn);
        float pp = __expf(alpha0 - mn);
        s  = s*rs + pp;
        a0 = a0*rs + pp*v0.x; a1 = a1*rs + pp*v0.y;
        a2 = a2*rs + pp*v0.z; a3 = a3*rs + pp*v0.w;
        m = mn;
        mn = fmaxf(m, alpha1);
        rs = __expf(m - mn);
        pp = __expf(alpha1 - mn);
        s  = s*rs + pp;
        a0 = a0*rs + pp*v1.x; a1 = a1*rs + pp*v1.y;
        a2 = a2*rs + pp*v1.z; a3 = a3*rs + pp*v1.w;
        m = mn;
        kw0 = kwn0; v0 = vn0; kw1 = kwn1; v1 = vn1;
    }
    const float inv = (s > 0.f) ? 1.f/s : 0.f;
    const float att[4] = { a0*inv, a1*inv, a2*inv, a3*inv };

    const float4 x4 = ld4(xr + (size_t)n * HC1 + c0);
    const float xx[4] = { x4.x, x4.y, x4.z, x4.w };
    float d = 0.f;
    #pragma unroll
    for (int j = 0; j < 4; ++j) {
        int c = c0 + j;
        d += att[j]*wb[c] + xx[j]*wb[HC1 + c] + (att[j]-xx[j])*wb[2*HC1 + c];
    }
    d = wave_red_sum(d);
    const float beta = 1.f / (1.f + __expf(-d));
    s16x4 hv4;
    #pragma unroll
    for (int j = 0; j < 4; ++j) {
        int c = c0 + j;
        float hv = beta*xx[j] + (1.f-beta)*att[j];
        hv = (hv - mean[c]) * rsqrtf(var[c] + 1e-5f) * g[c] + bbn[c];
        hv = hv > 0.f ? hv : expm1f(hv);
        hv4[j] = f2bf(hv);
    }
    *(s16x4*)(hb + (size_t)n * HC1 + c0) = hv4;
}

// ---------- fused layer-2 attention, edge-PAIR pipelined; K fp8, V bf16 ----------
__global__ void __launch_bounds__(64)
attn2_k(const int* __restrict__ offs, const int* __restrict__ slist,
        const short* __restrict__ qb, const unsigned char* __restrict__ kb,
        const short* __restrict__ vb,
        const short* __restrict__ xr, const float* __restrict__ wb,
        float* __restrict__ outp, int colofs)
{
    const int n = blockIdx.x;
    const int lane = threadIdx.x;
    const int c0 = lane * 2;
    const int lo = offs[n], hi = offs[n+1];
    const float2 q = ld2(qb + (size_t)n * HC2 + c0);
    const float scale = 0.088388347648318447f;   // 1/sqrt(128)

    float m = -INFINITY, s = 0.f;
    float a0 = 0.f, a1 = 0.f;
    unsigned kw0 = 0, kw1 = 0;
    float2 v0 = {0,0}, v1 = {0,0};
    if (lo < hi) {
        int sr = slist[lo];
        kw0 = *(const unsigned short*)(kb + (size_t)sr * HC2 + c0);
        v0 = ld2(vb + (size_t)sr * HC2 + c0);
    }
    if (lo + 1 < hi) {
        int sr = slist[lo + 1];
        kw1 = *(const unsigned short*)(kb + (size_t)sr * HC2 + c0);
        v1 = ld2(vb + (size_t)sr * HC2 + c0);
    }
    for (int i = lo; i < hi; i += 2) {
        unsigned kwn0 = 0, kwn1 = 0;
        float2 vn0 = {0,0}, vn1 = {0,0};
        if (i + 2 < hi) {
            int sr = slist[i + 2];
            kwn0 = *(const unsigned short*)(kb + (size_t)sr * HC2 + c0);
            vn0 = ld2(vb + (size_t)sr * HC2 + c0);
        }
        if (i + 3 < hi) {
            int sr = slist[i + 3];
            kwn1 = *(const unsigned short*)(kb + (size_t)sr * HC2 + c0);
            vn1 = ld2(vb + (size_t)sr * HC2 + c0);
        }
        const float2 k0 = dec_fp8x2(kw0);
        const float2 k1 = dec_fp8x2(kw1);
        float p0 = q.x*k0.x + q.y*k0.y;
        float p1 = q.x*k1.x + q.y*k1.y;
        #pragma unroll
        for (int off = 32; off >= 1; off >>= 1) {
            p0 += __shfl_xor(p0, off, 64);
            p1 += __shfl_xor(p1, off, 64);
        }
        const float alpha0 = p0 * scale;
        const float alpha1 = (i + 1 < hi) ? p1 * scale : -INFINITY;
        float mn = fmaxf(m, alpha0);
        float rs = __expf(m - mn);
        float pp = __expf(alpha0 - mn);
        s  = s*rs + pp;
        a0 = a0*rs + pp*v0.x; a1 = a1*rs + pp*v0.y;
        m = mn;
        mn = fmaxf(m, alpha1);
        rs = __expf(m - mn);
        pp = __expf(alpha1 - mn);
        s  = s*rs + pp;
        a0 = a0*rs + pp*v1.x; a1 = a1*rs + pp*v1.y;
        m = mn;
        kw0 = kwn0; v0 = vn0; kw1 = kwn1; v1 = vn1;
    }
    const float inv = (s > 0.f) ? 1.f/s : 0.f;
    const float att0 = a0*inv, att1 = a1*inv;

    const float2 x2 = ld2(xr + (size_t)n * HC2 + c0);
    float d = att0*wb[c0] + att1*wb[c0+1]
            + x2.x*wb[HC2+c0] + x2.y*wb[HC2+c0+1]
            + (att0-x2.x)*wb[2*HC2+c0] + (att1-x2.y)*wb[2*HC2+c0+1];
    d = wave_red_sum(d);
    const float beta = 1.f/(1.f+__expf(-d));
    outp[(size_t)n*(RR*HC2) + colofs + c0]     = beta*x2.x + (1.f-beta)*att0;
    outp[(size_t)n*(RR*HC2) + colofs + c0 + 1] = beta*x2.y + (1.f-beta)*att1;
}

extern "C" void kernel_launch(void* const* d_in, const int* in_sizes, int n_in,
                              void* d_out, int out_size, void* d_ws, size_t ws_size,
                              hipStream_t stream)
{
    const float* features = (const float*)d_in[0];
    const int*   n_ids    = (const int*)d_in[1];
    const int*   ei1      = (const int*)d_in[2];
    const int*   ei2      = (const int*)d_in[3];
    const float* wq1 = (const float*)d_in[4];  const float* bq1 = (const float*)d_in[5];
    const float* wk1 = (const float*)d_in[6];  const float* bk1 = (const float*)d_in[7];
    const float* wv1 = (const float*)d_in[8];  const float* bv1 = (const float*)d_in[9];
    const float* ws1 = (const float*)d_in[10]; const float* bs1 = (const float*)d_in[11];
    const float* wbeta1 = (const float*)d_in[12];
    const float* bn_g = (const float*)d_in[13]; const float* bn_b = (const float*)d_in[14];
    const float* bn_m = (const float*)d_in[15]; const float* bn_v = (const float*)d_in[16];
    const float* wq2 = (const float*)d_in[17]; const float* bq2 = (const float*)d_in[18];
    const float* wk2 = (const float*)d_in[19]; const float* bk2 = (const float*)d_in[20];
    const float* wv2 = (const float*)d_in[21]; const float* bv2 = (const float*)d_in[22];
    const float* ws2 = (const float*)d_in[23]; const float* bs2 = (const float*)d_in[24];
    const float* wbeta2 = (const float*)d_in[25];
    float* outp = (float*)d_out;

    // CSR build geometry
    constexpr int TS = 8192;
    constexpr int T1 = (NE1 + TS - 1) / TS;   // 37
    constexpr int T2 = (NE2 + TS - 1) / TS;   // 8
    constexpr int R1 = (NN1 + 511) >> 9;      // 40
    constexpr int R2 = (NB  + 511) >> 9;      // 8

    char* p = (char*)d_ws;
    auto alloc = [&](size_t bytes) { char* q = p; p += (bytes + 255) & ~(size_t)255; return q; };
    unsigned char* k1b = (unsigned char*)alloc((size_t)NN0*HC1);     // 20.5 MB fp8
    short* v1b  = (short*)alloc(sizeof(short)*(size_t)NN0*HC1);      // 41 MB bf16
    short* q1b  = (short*)alloc(sizeof(short)*(size_t)NN1*HC1);
    short* xr1  = (short*)alloc(sizeof(short)*(size_t)NN1*HC1);      // bf16
    short* hbf  = (short*)alloc(sizeof(short)*(size_t)NN1*HC1);
    short* xbf  = (short*)alloc(sizeof(short)*(size_t)NTOT*FIN);
    short* wt1  = (short*)alloc(sizeof(short)*(size_t)RR*4*FIN*HC1);
    short* wt2  = (short*)alloc(sizeof(short)*(size_t)RR*4*HC1*HC2);
    unsigned char* k2b = (unsigned char*)alloc((size_t)NN1*HC2);     // fp8
    short* v2b  = (short*)alloc(sizeof(short)*(size_t)NN1*HC2);
    short* q2b  = (short*)alloc(sizeof(short)*(size_t)NB*HC2);
    short* xr2  = (short*)alloc(sizeof(short)*(size_t)NB*HC2);       // bf16
    // CSR state (all replicas)
    int* offs1  = (int*)alloc(sizeof(int)*(size_t)RR*(NN1+1));
    int* slist1 = (int*)alloc(sizeof(int)*(size_t)RR*NE1);
    int* offs2  = (int*)alloc(sizeof(int)*(size_t)RR*(NB+1));
    int* slist2 = (int*)alloc(sizeof(int)*(size_t)RR*NE2);
    unsigned long long* scr1 = (unsigned long long*)alloc(sizeof(unsigned long long)*(size_t)RR*NE1);
    unsigned long long* scr2 = (unsigned long long*)alloc(sizeof(unsigned long long)*(size_t)RR*NE2);
    int* cnt_tr1  = (int*)alloc(sizeof(int)*(size_t)RR*R1*T1);
    int* base_tr1 = (int*)alloc(sizeof(int)*(size_t)RR*R1*T1);
    int* rbase1   = (int*)alloc(sizeof(int)*(size_t)RR*(R1+1));
    int* cnt_tr2  = (int*)alloc(sizeof(int)*(size_t)RR*R2*T2);
    int* base_tr2 = (int*)alloc(sizeof(int)*(size_t)RR*R2*T2);
    int* rbase2   = (int*)alloc(sizeof(int)*(size_t)RR*(R2+1));
    (void)ws_size; (void)in_sizes; (void)n_in; (void)out_size;

    // ---- prologue: conversions + weight packing ----
    fcvt_k<<<(NTOT*FIN/4 + 255)/256, 256, 0, stream>>>(features, xbf, NTOT*FIN/4);
    {
        dim3 g1(128, 4, RR);
        wpack_k<FIN, HC1><<<g1, 256, 0, stream>>>(wq1, wk1, wv1, ws1, wt1);
        dim3 g2(128, 4, RR);
        wpack_k<HC1, HC2><<<g2, 256, 0, stream>>>(wq2, wk2, wv2, ws2, wt2);
    }

    // ---- two-level CSR builds ----
    {
        dim3 ga1(T1, RR), ga2(T2, RR);
        csr_a1<TS><<<ga1, 256, 0, stream>>>(ei1, NE1, R1, T1, cnt_tr1);
        csr_a1<TS><<<ga2, 256, 0, stream>>>(ei2, NE2, R2, T2, cnt_tr2);
        csr_b<<<RR, 64, 0, stream>>>(cnt_tr1, R1, T1, NE1, NN1, base_tr1, rbase1, offs1);
        csr_b<<<RR, 64, 0, stream>>>(cnt_tr2, R2, T2, NE2, NB,  base_tr2, rbase2, offs2);
        csr_a2<TS><<<ga1, 256, 0, stream>>>(ei1, NE1, R1, T1, base_tr1, scr1);
        csr_a2<TS><<<ga2, 256, 0, stream>>>(ei2, NE2, R2, T2, base_tr2, scr2);
        dim3 gc1(R1, RR), gc2(R2, RR);
        csr_c<<<gc1, 256, 0, stream>>>(scr1, rbase1, NE1, R1, NN1, offs1, slist1);
        csr_c<<<gc2, 256, 0, stream>>>(scr2, rbase2, NE2, R2, NB,  offs2, slist2);
    }

    const size_t WSZ = (size_t)FIN*HC1;

    for (int r = 0; r < RR; ++r) {
        const int* nid  = n_ids + (size_t)r*NN0;
        const short* ptq1 = wt1 + ((size_t)r*4 + 0)*WSZ;
        const short* ptk1 = wt1 + ((size_t)r*4 + 1)*WSZ;
        const short* ptv1 = wt1 + ((size_t)r*4 + 2)*WSZ;
        const short* pts1 = wt1 + ((size_t)r*4 + 3)*WSZ;
        const short* ptq2 = wt2 + ((size_t)r*4 + 0)*WSZ;
        const short* ptk2 = wt2 + ((size_t)r*4 + 1)*WSZ;
        const short* ptv2 = wt2 + ((size_t)r*4 + 2)*WSZ;
        const short* pts2 = wt2 + ((size_t)r*4 + 3)*WSZ;

        // ---- layer 1 projections (MFMA, fused gather; K fp8, V bf16) ----
        gemm2l<FIN, HC1, unsigned char, short><<<NN0/32, 256, 0, stream>>>(
            xbf, FIN, nid, ptk1, bk1 + r*HC1, k1b, ptv1, bv1 + r*HC1, v1b);
        gemm2l<FIN, HC1, short, short><<<NN1/32, 256, 0, stream>>>(
            xbf, FIN, nid, ptq1, bq1 + r*HC1, q1b, pts1, bs1 + r*HC1, xr1);

        // ---- layer 1 fused attention + epilogue ----
        attn1_k<<<NN1, 64, 0, stream>>>(offs1 + (size_t)r*(NN1+1), slist1 + (size_t)r*NE1,
            q1b, k1b, v1b, xr1,
            wbeta1 + (size_t)r*3*HC1,
            bn_g + (size_t)r*HC1, bn_b + (size_t)r*HC1,
            bn_m + (size_t)r*HC1, bn_v + (size_t)r*HC1, hbf);

        // ---- layer 2 projections (MFMA; K fp8, V bf16) ----
        gemm2l<HC1, HC2, unsigned char, short><<<NN1/32, 256, 0, stream>>>(
            hbf, HC1, nullptr, ptk2, bk2 + r*HC2, k2b, ptv2, bv2 + r*HC2, v2b);
        gemm2l<HC1, HC2, short, short><<<NB/32, 256, 0, stream>>>(
            hbf, HC1, nullptr, ptq2, bq2 + r*HC2, q2b, pts2, bs2 + r*HC2, xr2);

        // ---- layer 2 fused attention + output ----
        attn2_k<<<NB, 64, 0, stream>>>(offs2 + (size_t)r*(NB+1), slist2 + (size_t)r*NE2,
            q2b, k2b, v2b, xr2,
            wbeta2 + (size_t)r*3*HC2, outp, r*HC2);
    }
}